// Round 3
// baseline (1739.222 us; speedup 1.0000x reference)
//
#include <hip/hip_runtime.h>
#include <hip/hip_bf16.h>

#define B_ 4
#define S_ 4096
#define E_ 1024
#define H_ 16
#define D_ 64
#define NS_ 1024
#define M_ (B_*S_)
#define K_ E_
#define DELTA 0.05f
#define BANDCAP 192

typedef __attribute__((ext_vector_type(8))) short bf16x8;
typedef __attribute__((ext_vector_type(4))) float floatx4;

#define THSTEP 0.00038349519697141023f  /* (pi/2)/4096 */

__device__ inline float bf16_to_f(unsigned short u) {
    return __uint_as_float(((unsigned)u) << 16);
}
__device__ inline unsigned short f_to_bf16(float f) {
    unsigned u = __float_as_uint(f);
    unsigned r = (u + 0x7FFFu + ((u >> 16) & 1u)) >> 16;  // RNE
    return (unsigned short)r;
}
__device__ inline void split2(float f, unsigned short& h, unsigned short& l) {
    h = f_to_bf16(f);
    l = f_to_bf16(f - bf16_to_f(h));   // residual exact in fp32 (within 2x)
}

// ---------------------------------------------------------------------------
// Kernel 1: QKV projection GEMM, fp32 inputs, split-bf16 MFMA.
// C[m,n] = sum_k x[m,k]*W[n,k] + b[n].  128x128 tile, 4 waves, BK=64.
// Staging converts fp32 -> (hi,lo) bf16 tiles in LDS (XOR-swizzled chunks).
// w<2 (q,k): 3 products hh+hl+lh (accurate scores); w==2 (v): hh only.
// ---------------------------------------------------------------------------
__global__ __launch_bounds__(256) void qkv_gemm(
    const float* __restrict__ x,
    const float* __restrict__ Wq, const float* __restrict__ bq,
    const float* __restrict__ Wk, const float* __restrict__ bk,
    const float* __restrict__ Wv, const float* __restrict__ bv,
    float* __restrict__ q32, float* __restrict__ k32, ushort* __restrict__ v16)
{
    __shared__ __align__(16) ushort Ash[128 * 64];
    __shared__ __align__(16) ushort Asl[128 * 64];
    __shared__ __align__(16) ushort Bsh[128 * 64];
    __shared__ __align__(16) ushort Bsl[128 * 64];

    const int w = blockIdx.z;
    const float* W    = (w == 0) ? Wq : (w == 1) ? Wk : Wv;
    const float* bias = (w == 0) ? bq : (w == 1) ? bk : bv;
    const bool need_lo = (w < 2);

    const int m0 = blockIdx.y * 128;
    const int n0 = blockIdx.x * 128;
    const int t = threadIdx.x;
    const int wave = t >> 6, lane = t & 63;
    const int wm = (wave >> 1) * 64, wn = (wave & 1) * 64;
    const int m16 = lane & 15, quad = lane >> 4;

    floatx4 acc[4][4];
#pragma unroll
    for (int i = 0; i < 4; i++)
#pragma unroll
        for (int j = 0; j < 4; j++) acc[i][j] = (floatx4){0.f, 0.f, 0.f, 0.f};

    for (int ks = 0; ks < K_ / 64; ++ks) {
        const int k0 = ks * 64;
#pragma unroll
        for (int i = 0; i < 8; i++) {
            int eid = (i * 256 + t) * 4;        // element id in 128x64 tile
            int r = eid >> 6, e = eid & 63;
            int g = e >> 3, half = (e >> 2) & 1;
            int col = g ^ (r & 7);              // XOR chunk swizzle
            int loff = (r * 8 + col) * 8 + half * 4;

            float4 av = *(const float4*)(x + (size_t)(m0 + r) * K_ + k0 + e);
            ushort4 hh, ll;
            split2(av.x, hh.x, ll.x); split2(av.y, hh.y, ll.y);
            split2(av.z, hh.z, ll.z); split2(av.w, hh.w, ll.w);
            *(ushort4*)&Ash[loff] = hh;
            if (need_lo) *(ushort4*)&Asl[loff] = ll;

            float4 bvv = *(const float4*)(W + (size_t)(n0 + r) * K_ + k0 + e);
            split2(bvv.x, hh.x, ll.x); split2(bvv.y, hh.y, ll.y);
            split2(bvv.z, hh.z, ll.z); split2(bvv.w, hh.w, ll.w);
            *(ushort4*)&Bsh[loff] = hh;
            if (need_lo) *(ushort4*)&Bsl[loff] = ll;
        }
        __syncthreads();
#pragma unroll
        for (int kk = 0; kk < 2; ++kk) {
            bf16x8 ah[4], al[4], bh[4], bl[4];
            const int g = kk * 4 + quad;
#pragma unroll
            for (int mt = 0; mt < 4; ++mt) {
                int r = wm + mt * 16 + m16;
                int o = ((r * 8 + (g ^ (r & 7))) * 8);
                ah[mt] = *(const bf16x8*)&Ash[o];
                if (need_lo) al[mt] = *(const bf16x8*)&Asl[o];
                int r2 = wn + mt * 16 + m16;
                int o2 = ((r2 * 8 + (g ^ (r2 & 7))) * 8);
                bh[mt] = *(const bf16x8*)&Bsh[o2];
                if (need_lo) bl[mt] = *(const bf16x8*)&Bsl[o2];
            }
#pragma unroll
            for (int mt = 0; mt < 4; ++mt)
#pragma unroll
                for (int nt = 0; nt < 4; ++nt) {
                    acc[mt][nt] = __builtin_amdgcn_mfma_f32_16x16x32_bf16(
                        ah[mt], bh[nt], acc[mt][nt], 0, 0, 0);
                    if (need_lo) {
                        acc[mt][nt] = __builtin_amdgcn_mfma_f32_16x16x32_bf16(
                            ah[mt], bl[nt], acc[mt][nt], 0, 0, 0);
                        acc[mt][nt] = __builtin_amdgcn_mfma_f32_16x16x32_bf16(
                            al[mt], bh[nt], acc[mt][nt], 0, 0, 0);
                    }
                }
        }
        __syncthreads();
    }

    // epilogue:  C row = quad*4+reg, col = lane&15  [m89/m91 verified layout]
    float biasv[4];
#pragma unroll
    for (int nt = 0; nt < 4; nt++)
        biasv[nt] = bias[n0 + wn + nt * 16 + m16];

    if (w < 2) {
        float* dst = (w == 0) ? q32 : k32;
#pragma unroll
        for (int mt = 0; mt < 4; ++mt)
#pragma unroll
            for (int nt = 0; nt < 4; ++nt) {
                int colg = n0 + wn + nt * 16 + m16;
#pragma unroll
                for (int reg = 0; reg < 4; ++reg) {
                    int rowg = m0 + wm + mt * 16 + quad * 4 + reg;
                    dst[(size_t)rowg * E_ + colg] = acc[mt][nt][reg] + biasv[nt];
                }
            }
    } else {
#pragma unroll
        for (int mt = 0; mt < 4; ++mt)
#pragma unroll
            for (int nt = 0; nt < 4; ++nt) {
                int colg = n0 + wn + nt * 16 + m16;
#pragma unroll
                for (int reg = 0; reg < 4; ++reg) {
                    int rowg = m0 + wm + mt * 16 + quad * 4 + reg;
                    v16[(size_t)rowg * E_ + colg] = f_to_bf16(acc[mt][nt][reg] + biasv[nt]);
                }
            }
    }
}

// ---------------------------------------------------------------------------
// Kernel 2: approx scores[b,h,s] = sum_d q*k (raw q,k fp32). one wave/token
// ---------------------------------------------------------------------------
__global__ __launch_bounds__(256) void scores_kernel(
    const float* __restrict__ q32, const float* __restrict__ k32,
    float* __restrict__ scores)
{
    int wid = blockIdx.x * 4 + (threadIdx.x >> 6);
    int lane = threadIdx.x & 63;
    int s = wid & (S_ - 1);
    int bh = wid >> 12;
    int b = bh >> 4, h = bh & 15;
    size_t addr = (size_t)(b * S_ + s) * E_ + h * 64 + lane;
    float p = q32[addr] * k32[addr];
#pragma unroll
    for (int m = 32; m; m >>= 1) p += __shfl_xor(p, m, 64);
    if (lane == 0) scores[wid] = p;
}

// ---------------------------------------------------------------------------
// Kernel 3: per-(b,h): radix-select 1024th approx score T_a; classify tokens:
//   score > T_a+DELTA  -> definite in (selidx[0..cnt_in))
//   |score-T_a|<=DELTA -> band list (exact rescoring downstream)
// ---------------------------------------------------------------------------
__global__ __launch_bounds__(256) void band_select_kernel(
    const float* __restrict__ scores, int* __restrict__ selidx,
    int* __restrict__ band, int* __restrict__ meta)
{
    __shared__ unsigned keys[4096];
    __shared__ unsigned hist[256];
    __shared__ unsigned bcast[2];
    __shared__ int cnt_in, cnt_band;

    int bh = blockIdx.x;
    int t = threadIdx.x;
    const float* sc = scores + (size_t)bh * S_;

    for (int i = t; i < 4096; i += 256) {
        unsigned u = __float_as_uint(sc[i]);
        u = (u & 0x80000000u) ? ~u : (u | 0x80000000u);
        keys[i] = u;
    }
    if (t == 0) { cnt_in = 0; cnt_band = 0; }
    __syncthreads();

    unsigned prefix = 0, want = NS_;
    for (int shift = 24; shift >= 0; shift -= 8) {
        hist[t] = 0;
        __syncthreads();
        unsigned pmask = (shift == 24) ? 0u : (0xFFFFFFFFu << (shift + 8));
        for (int i = t; i < 4096; i += 256) {
            unsigned ky = keys[i];
            if ((ky & pmask) == prefix) atomicAdd(&hist[(ky >> shift) & 255u], 1u);
        }
        __syncthreads();
        if (t == 0) {
            unsigned wv = want;
            int bsel = 0;
            for (int bb = 255; bb >= 0; --bb) {
                unsigned c = hist[bb];
                if (c >= wv) { bsel = bb; break; }
                wv -= c;
            }
            bcast[0] = (unsigned)bsel; bcast[1] = wv;
        }
        __syncthreads();
        prefix = prefix | (bcast[0] << shift);
        want = bcast[1];
        __syncthreads();
    }
    // invert key -> float value of the 1024th-largest approx score
    unsigned fb = (prefix & 0x80000000u) ? (prefix ^ 0x80000000u) : ~prefix;
    float Ta = __uint_as_float(fb);
    float Thi = Ta + DELTA, Tlo = Ta - DELTA;

    int* sel = selidx + (size_t)bh * NS_;
    int* bnd = band + (size_t)bh * BANDCAP;
    for (int i = t; i < 4096; i += 256) {
        float v = sc[i];
        if (v > Thi) {
            int p = atomicAdd(&cnt_in, 1);
            sel[p] = i;
        } else if (v >= Tlo) {
            int p = atomicAdd(&cnt_band, 1);
            if (p < BANDCAP) bnd[p] = i;
        }
    }
    __syncthreads();
    if (t == 0) {
        meta[bh * 2 + 0] = cnt_in;
        meta[bh * 2 + 1] = (cnt_band < BANDCAP) ? cnt_band : BANDCAP;
    }
}

// ---------------------------------------------------------------------------
// Kernel 4: exact fp64 rescoring of band tokens + final in-band selection.
// One block per (b,h). Threads 0..127: fp64 dot (len 1024) for q (t<64) / k.
// ---------------------------------------------------------------------------
__global__ __launch_bounds__(256) void band_exact_kernel(
    const float* __restrict__ x,
    const float* __restrict__ Wq, const float* __restrict__ Wk,
    const int* __restrict__ band, const int* __restrict__ meta,
    int* __restrict__ selidx)
{
    __shared__ double qk[128];
    __shared__ double bs[BANDCAP];
    __shared__ int bidx[BANDCAP];
    __shared__ int selc;

    int bh = blockIdx.x;
    int b = bh >> 4, h = bh & 15;
    int t = threadIdx.x;
    int cnt_in = meta[bh * 2 + 0];
    int NB = meta[bh * 2 + 1];
    int need = NS_ - cnt_in;
    if (t == 0) selc = 0;

    for (int j = t; j < NB; j += 256) bidx[j] = band[(size_t)bh * BANDCAP + j];
    __syncthreads();

    for (int j = 0; j < NB; ++j) {
        int s = bidx[j];
        if (t < 128) {
            int d = t & 63;
            const float* wrow = ((t < 64) ? Wq : Wk) + (size_t)(h * 64 + d) * K_;
            const float* xrow = x + (size_t)(b * S_ + s) * K_;
            double a = 0.0;
            for (int k4 = 0; k4 < K_ / 4; ++k4) {
                float4 xv = *(const float4*)(xrow + k4 * 4);
                float4 wv = *(const float4*)(wrow + k4 * 4);
                a += (double)xv.x * (double)wv.x;
                a += (double)xv.y * (double)wv.y;
                a += (double)xv.z * (double)wv.z;
                a += (double)xv.w * (double)wv.w;
            }
            qk[t] = a;
        }
        __syncthreads();
        if (t == 0) {
            double sum = 0.0;
            for (int d = 0; d < 64; ++d) sum += qk[d] * qk[64 + d];
            bs[j] = sum;
        }
        __syncthreads();
    }

    // rank band tokens by exact score (ties -> lower index), take top `need`
    int* sel = selidx + (size_t)bh * NS_ + cnt_in;
    for (int j = t; j < NB; j += 256) {
        double mine = bs[j];
        int myi = bidx[j];
        int r = 0;
        for (int j2 = 0; j2 < NB; ++j2)
            r += (bs[j2] > mine) || (bs[j2] == mine && bidx[j2] < myi);
        if (r < need) {
            int p = atomicAdd(&selc, 1);
            sel[p] = myi;
        }
    }
}

// ---------------------------------------------------------------------------
// Kernel 5: partial KV reductions. kvp[bh][ch][{cos,sin}][d][e] over 512 tokens
// ---------------------------------------------------------------------------
__global__ __launch_bounds__(256) void kv_partial_kernel(
    const float* __restrict__ k32, const ushort* __restrict__ v16,
    float* __restrict__ kvp)
{
    int ch = blockIdx.x;   // 0..7
    int bh = blockIdx.y;   // 0..63
    int b = bh >> 4, h = bh & 15;
    int t = threadIdx.x;
    int d0 = (t >> 4) * 4, e0 = (t & 15) * 4;

    float accC[4][4] = {}, accS[4][4] = {};
    const float* kb = k32 + (size_t)b * S_ * E_ + h * 64 + d0;
    const ushort* vb = v16 + (size_t)b * S_ * E_ + h * 64 + e0;
    int s0 = ch * (S_ / 8);

    for (int si = 0; si < S_ / 8; ++si) {
        int s = s0 + si;
        float th = (float)s * THSTEP;
        float cw = __cosf(th), sw = __sinf(th);
        float4 kf = *(const float4*)(kb + (size_t)s * E_);
        ushort4 vu = *(const ushort4*)(vb + (size_t)s * E_);
        float kr[4] = { fmaxf(kf.x, 0.f), fmaxf(kf.y, 0.f),
                        fmaxf(kf.z, 0.f), fmaxf(kf.w, 0.f) };
        float vv[4] = { bf16_to_f(vu.x), bf16_to_f(vu.y),
                        bf16_to_f(vu.z), bf16_to_f(vu.w) };
        float kc[4], ksn[4];
#pragma unroll
        for (int i = 0; i < 4; i++) { kc[i] = kr[i] * cw; ksn[i] = kr[i] * sw; }
#pragma unroll
        for (int i = 0; i < 4; i++)
#pragma unroll
            for (int j = 0; j < 4; j++) {
                accC[i][j] += kc[i] * vv[j];
                accS[i][j] += ksn[i] * vv[j];
            }
    }
    float* pc = kvp + ((size_t)(bh * 8 + ch) * 2) * 4096;
    float* ps = pc + 4096;
#pragma unroll
    for (int i = 0; i < 4; i++)
#pragma unroll
        for (int j = 0; j < 4; j++) {
            pc[(d0 + i) * 64 + (e0 + j)] = accC[i][j];
            ps[(d0 + i) * 64 + (e0 + j)] = accS[i][j];
        }
}

// Kernel 6: reduce the 8 partials -> kv[bh][{cos,sin}][64][64]
__global__ __launch_bounds__(256) void kv_reduce_kernel(
    const float* __restrict__ kvp, float* __restrict__ kv)
{
    int i = blockIdx.x * 256 + threadIdx.x;   // 0 .. 64*2*4096-1
    if (i >= 64 * 2 * 4096) return;
    int bh = i >> 13;
    int rem = i & 8191;
    const float* p = kvp + (size_t)bh * 8 * 8192 + rem;
    float a = 0.f;
#pragma unroll
    for (int c = 0; c < 8; c++) a += p[c * 8192];
    kv[i] = a;
}

// ---------------------------------------------------------------------------
// Kernel 7: sampled = qs_cos @ kv_cos + qs_sin @ kv_sin, scattered to out rows
// ---------------------------------------------------------------------------
__global__ __launch_bounds__(256) void sampled_kernel(
    const float* __restrict__ q32, const int* __restrict__ selidx,
    const float* __restrict__ kv, float* __restrict__ out)
{
    __shared__ float kvc[4096];
    __shared__ float kvs[4096];
    int bh = blockIdx.y;
    int b = bh >> 4, h = bh & 15;
    int t = threadIdx.x;
    const float* kvsrc = kv + (size_t)bh * 8192;
    for (int i = t; i < 4096; i += 256) {
        kvc[i] = kvsrc[i];
        kvs[i] = kvsrc[4096 + i];
    }
    __syncthreads();

    int n = blockIdx.x * 256 + t;
    int s = selidx[(size_t)bh * NS_ + n];
    const float* qr = q32 + (size_t)(b * S_ + s) * E_ + h * 64;
    float th = (float)s * THSTEP;
    float cw = __cosf(th), sw = __sinf(th);

    float acc[64];
#pragma unroll
    for (int e = 0; e < 64; e++) acc[e] = 0.f;

    for (int d = 0; d < 64; ++d) {
        float qd = fmaxf(qr[d], 0.f);
        float a = qd * cw, bb = qd * sw;
        const float4* pc4 = (const float4*)&kvc[d * 64];
        const float4* ps4 = (const float4*)&kvs[d * 64];
#pragma unroll
        for (int e4 = 0; e4 < 16; e4++) {
            float4 c4 = pc4[e4], s4 = ps4[e4];
            acc[e4 * 4 + 0] += a * c4.x + bb * s4.x;
            acc[e4 * 4 + 1] += a * c4.y + bb * s4.y;
            acc[e4 * 4 + 2] += a * c4.z + bb * s4.z;
            acc[e4 * 4 + 3] += a * c4.w + bb * s4.w;
        }
    }
    float* orow = out + (size_t)(b * S_ + s) * E_ + h * 64;
#pragma unroll
    for (int e = 0; e < 64; e++) orow[e] = acc[e];
}

__global__ void zero_kernel(uint4* __restrict__ p, int n16)
{
    int stride = gridDim.x * blockDim.x;
    for (int i = blockIdx.x * blockDim.x + threadIdx.x; i < n16; i += stride)
        p[i] = make_uint4(0u, 0u, 0u, 0u);
}

extern "C" void kernel_launch(void* const* d_in, const int* in_sizes, int n_in,
                              void* d_out, int out_size, void* d_ws, size_t ws_size,
                              hipStream_t stream)
{
    const float* x  = (const float*)d_in[0];
    const float* Wq = (const float*)d_in[1];
    const float* bq = (const float*)d_in[2];
    const float* Wk = (const float*)d_in[3];
    const float* bk = (const float*)d_in[4];
    const float* Wv = (const float*)d_in[5];
    const float* bv = (const float*)d_in[6];

    char* ws = (char*)d_ws;
    float*  q32    = (float*)(ws);                    // 67,108,864 B
    float*  k32    = (float*)(ws + 67108864);         // 67,108,864 B
    ushort* v16    = (ushort*)(ws + 134217728);       // 33,554,432 B
    float*  scores = (float*)(ws + 167772160);        //  1,048,576 B
    int*    selidx = (int*)(ws + 168820736);          //    262,144 B
    int*    band   = (int*)(ws + 169082880);          //     49,152 B
    int*    meta   = (int*)(ws + 169132032);          //        512 B
    float*  kvp    = (float*)(ws + 169132544);        // 16,777,216 B
    float*  kv     = (float*)(ws + 185909760);        //  2,097,152 B (end ~179.3 MiB)
    float*  out    = (float*)d_out;

    hipLaunchKernelGGL(zero_kernel, dim3(2048), dim3(256), 0, stream,
                       (uint4*)out, (int)((size_t)M_ * E_ * 4 / 16));
    hipLaunchKernelGGL(qkv_gemm, dim3(8, 128, 3), dim3(256), 0, stream,
                       x, Wq, bq, Wk, bk, Wv, bv, q32, k32, v16);
    hipLaunchKernelGGL(scores_kernel, dim3((B_ * H_ * S_) / 4), dim3(256), 0, stream,
                       q32, k32, scores);
    hipLaunchKernelGGL(band_select_kernel, dim3(B_ * H_), dim3(256), 0, stream,
                       scores, selidx, band, meta);
    hipLaunchKernelGGL(band_exact_kernel, dim3(B_ * H_), dim3(256), 0, stream,
                       x, Wq, Wk, band, meta, selidx);
    hipLaunchKernelGGL(kv_partial_kernel, dim3(8, 64), dim3(256), 0, stream,
                       k32, v16, kvp);
    hipLaunchKernelGGL(kv_reduce_kernel, dim3(2048), dim3(256), 0, stream,
                       kvp, kv);
    hipLaunchKernelGGL(sampled_kernel, dim3(NS_ / 256, B_ * H_), dim3(256), 0, stream,
                       q32, selidx, kv, out);
}

// Round 4
// 1399.222 us; speedup vs baseline: 1.2430x; 1.2430x over previous
//
#include <hip/hip_runtime.h>
#include <hip/hip_bf16.h>

#define B_ 4
#define S_ 4096
#define E_ 1024
#define H_ 16
#define D_ 64
#define NS_ 1024
#define M_ (B_*S_)
#define K_ E_
#define DELTA 0.12f
#define BANDCAP 96

typedef __attribute__((ext_vector_type(8))) short bf16x8;
typedef __attribute__((ext_vector_type(4))) float floatx4;

#define THSTEP 0.00038349519697141023f  /* (pi/2)/4096 */

__device__ inline float bf16_to_f(unsigned short u) {
    return __uint_as_float(((unsigned)u) << 16);
}
__device__ inline unsigned short f_to_bf16(float f) {
    unsigned u = __float_as_uint(f);
    unsigned r = (u + 0x7FFFu + ((u >> 16) & 1u)) >> 16;  // RNE
    return (unsigned short)r;
}

// ---------------------------------------------------------------------------
// Split pass 1: x (fp32) -> xh (bf16 round)
// ---------------------------------------------------------------------------
__global__ __launch_bounds__(256) void split_x_kernel(
    const float* __restrict__ x, ushort* __restrict__ xh)
{
    int i = blockIdx.x * 256 + threadIdx.x;          // over float4s, exact grid
    float4 v = ((const float4*)x)[i];
    ushort4 hh;
    hh.x = f_to_bf16(v.x); hh.y = f_to_bf16(v.y);
    hh.z = f_to_bf16(v.z); hh.w = f_to_bf16(v.w);
    ((ushort4*)xh)[i] = hh;
}

// Split pass 2: Wq,Wk -> hi+lo bf16; Wv -> hi only
__global__ __launch_bounds__(256) void split_w_kernel(
    const float* __restrict__ Wq, const float* __restrict__ Wk,
    const float* __restrict__ Wv,
    ushort* __restrict__ Wqh, ushort* __restrict__ Wql,
    ushort* __restrict__ Wkh, ushort* __restrict__ Wkl,
    ushort* __restrict__ Wvh)
{
    int i = blockIdx.x * 256 + threadIdx.x;          // over float4s, exact grid
    float4 q = ((const float4*)Wq)[i];
    float4 k = ((const float4*)Wk)[i];
    float4 v = ((const float4*)Wv)[i];
    ushort4 h, l;
    h.x=f_to_bf16(q.x); l.x=f_to_bf16(q.x-bf16_to_f(h.x));
    h.y=f_to_bf16(q.y); l.y=f_to_bf16(q.y-bf16_to_f(h.y));
    h.z=f_to_bf16(q.z); l.z=f_to_bf16(q.z-bf16_to_f(h.z));
    h.w=f_to_bf16(q.w); l.w=f_to_bf16(q.w-bf16_to_f(h.w));
    ((ushort4*)Wqh)[i]=h; ((ushort4*)Wql)[i]=l;
    h.x=f_to_bf16(k.x); l.x=f_to_bf16(k.x-bf16_to_f(h.x));
    h.y=f_to_bf16(k.y); l.y=f_to_bf16(k.y-bf16_to_f(h.y));
    h.z=f_to_bf16(k.z); l.z=f_to_bf16(k.z-bf16_to_f(h.z));
    h.w=f_to_bf16(k.w); l.w=f_to_bf16(k.w-bf16_to_f(h.w));
    ((ushort4*)Wkh)[i]=h; ((ushort4*)Wkl)[i]=l;
    h.x=f_to_bf16(v.x); h.y=f_to_bf16(v.y);
    h.z=f_to_bf16(v.z); h.w=f_to_bf16(v.w);
    ((ushort4*)Wvh)[i]=h;
}

// ---------------------------------------------------------------------------
// Kernel 1: QKV GEMM, pure bf16, register-double-buffered staging.
// q,k: K-extent 2048 (A=xh both passes, B = Wh then Wl)  -> fp32 out
// v:   K-extent 1024 (hh only)                           -> bf16 out
// 128x128 tile, 4 waves, BK=64, XOR-swizzled LDS chunks, ds_read_b128 frags.
// ---------------------------------------------------------------------------
__global__ __launch_bounds__(256) void qkv_gemm(
    const ushort* __restrict__ xh,
    const ushort* __restrict__ Wqh, const ushort* __restrict__ Wql,
    const ushort* __restrict__ Wkh, const ushort* __restrict__ Wkl,
    const ushort* __restrict__ Wvh,
    const float* __restrict__ bq, const float* __restrict__ bk,
    const float* __restrict__ bv,
    float* __restrict__ q32, float* __restrict__ k32, ushort* __restrict__ v16)
{
    __shared__ __align__(16) ushort As[128 * 64];
    __shared__ __align__(16) ushort Bs[128 * 64];

    const int w = blockIdx.z;
    const ushort* Bhp = (w == 0) ? Wqh : (w == 1) ? Wkh : Wvh;
    const ushort* Blp = (w == 0) ? Wql : Wkl;      // unused when w==2
    const float* bias = (w == 0) ? bq : (w == 1) ? bk : bv;
    const int NK = (w < 2) ? 32 : 16;

    const int m0 = blockIdx.y * 128;
    const int n0 = blockIdx.x * 128;
    const int t = threadIdx.x;
    const int wave = t >> 6, lane = t & 63;
    const int wm = (wave >> 1) * 64, wn = (wave & 1) * 64;
    const int m16 = lane & 15, quad = lane >> 4;

    floatx4 acc[4][4];
#pragma unroll
    for (int i = 0; i < 4; i++)
#pragma unroll
        for (int j = 0; j < 4; j++) acc[i][j] = (floatx4){0.f, 0.f, 0.f, 0.f};

    // per-thread constant staging offsets (32-bit element offsets)
    int aoff[4], boff[4], lofs[4];
#pragma unroll
    for (int i = 0; i < 4; i++) {
        int slot = i * 256 + t;
        int r = slot >> 3, c = slot & 7, g = c ^ (r & 7);
        aoff[i] = (m0 + r) * K_ + g * 8;
        boff[i] = (n0 + r) * K_ + g * 8;
        lofs[i] = slot * 8;
    }

    uint4 ar[4], br[4];
#pragma unroll
    for (int i = 0; i < 4; i++) {                    // prologue: ks=0 (hi, kcol=0)
        ar[i] = *(const uint4*)(xh + aoff[i]);
        br[i] = *(const uint4*)(Bhp + boff[i]);
    }

    for (int ks = 0; ks < NK; ++ks) {
        __syncthreads();
#pragma unroll
        for (int i = 0; i < 4; i++) {
            *(uint4*)&As[lofs[i]] = ar[i];
            *(uint4*)&Bs[lofs[i]] = br[i];
        }
        __syncthreads();

        int ks1 = ks + 1;
        if (ks1 < NK) {                              // prefetch next tile -> regs
            int kcol = (ks1 & 15) * 64;
            const ushort* Bsrc = (ks1 >= 16) ? Blp : Bhp;
#pragma unroll
            for (int i = 0; i < 4; i++) {
                ar[i] = *(const uint4*)(xh + aoff[i] + kcol);
                br[i] = *(const uint4*)(Bsrc + boff[i] + kcol);
            }
        }

#pragma unroll
        for (int kk = 0; kk < 2; ++kk) {
            bf16x8 af[4], bfr[4];
            const int g = kk * 4 + quad;
#pragma unroll
            for (int mt = 0; mt < 4; ++mt) {
                int r = wm + mt * 16 + m16;
                af[mt] = *(const bf16x8*)&As[(r * 8 + (g ^ (r & 7))) * 8];
                int r2 = wn + mt * 16 + m16;
                bfr[mt] = *(const bf16x8*)&Bs[(r2 * 8 + (g ^ (r2 & 7))) * 8];
            }
#pragma unroll
            for (int mt = 0; mt < 4; ++mt)
#pragma unroll
                for (int nt = 0; nt < 4; ++nt)
                    acc[mt][nt] = __builtin_amdgcn_mfma_f32_16x16x32_bf16(
                        af[mt], bfr[nt], acc[mt][nt], 0, 0, 0);
        }
    }

    // epilogue:  C row = quad*4+reg, col = lane&15  [m89/m91 verified layout]
    float biasv[4];
#pragma unroll
    for (int nt = 0; nt < 4; nt++)
        biasv[nt] = bias[n0 + wn + nt * 16 + m16];

    if (w < 2) {
        float* dst = (w == 0) ? q32 : k32;
#pragma unroll
        for (int mt = 0; mt < 4; ++mt)
#pragma unroll
            for (int nt = 0; nt < 4; ++nt) {
                int colg = n0 + wn + nt * 16 + m16;
#pragma unroll
                for (int reg = 0; reg < 4; ++reg) {
                    int rowg = m0 + wm + mt * 16 + quad * 4 + reg;
                    dst[(size_t)rowg * E_ + colg] = acc[mt][nt][reg] + biasv[nt];
                }
            }
    } else {
#pragma unroll
        for (int mt = 0; mt < 4; ++mt)
#pragma unroll
            for (int nt = 0; nt < 4; ++nt) {
                int colg = n0 + wn + nt * 16 + m16;
#pragma unroll
                for (int reg = 0; reg < 4; ++reg) {
                    int rowg = m0 + wm + mt * 16 + quad * 4 + reg;
                    v16[(size_t)rowg * E_ + colg] = f_to_bf16(acc[mt][nt][reg] + biasv[nt]);
                }
            }
    }
}

// ---------------------------------------------------------------------------
// Kernel 2: approx scores[b,h,s] = sum_d q*k (raw q,k fp32). one wave/token
// ---------------------------------------------------------------------------
__global__ __launch_bounds__(256) void scores_kernel(
    const float* __restrict__ q32, const float* __restrict__ k32,
    float* __restrict__ scores)
{
    int wid = blockIdx.x * 4 + (threadIdx.x >> 6);
    int lane = threadIdx.x & 63;
    int s = wid & (S_ - 1);
    int bh = wid >> 12;
    int b = bh >> 4, h = bh & 15;
    size_t addr = (size_t)(b * S_ + s) * E_ + h * 64 + lane;
    float p = q32[addr] * k32[addr];
#pragma unroll
    for (int m = 32; m; m >>= 1) p += __shfl_xor(p, m, 64);
    if (lane == 0) scores[wid] = p;
}

// ---------------------------------------------------------------------------
// Kernel 3: radix-select 1024th approx score T_a; classify into definite-in
// (> T_a+DELTA) and band (|score-T_a| <= DELTA).
// ---------------------------------------------------------------------------
__global__ __launch_bounds__(256) void band_select_kernel(
    const float* __restrict__ scores, int* __restrict__ selidx,
    int* __restrict__ band, int* __restrict__ meta)
{
    __shared__ unsigned keys[4096];
    __shared__ unsigned hist[256];
    __shared__ unsigned bcast[2];
    __shared__ int cnt_in, cnt_band;

    int bh = blockIdx.x;
    int t = threadIdx.x;
    const float* sc = scores + (size_t)bh * S_;

    for (int i = t; i < 4096; i += 256) {
        unsigned u = __float_as_uint(sc[i]);
        u = (u & 0x80000000u) ? ~u : (u | 0x80000000u);
        keys[i] = u;
    }
    if (t == 0) { cnt_in = 0; cnt_band = 0; }
    __syncthreads();

    unsigned prefix = 0, want = NS_;
    for (int shift = 24; shift >= 0; shift -= 8) {
        hist[t] = 0;
        __syncthreads();
        unsigned pmask = (shift == 24) ? 0u : (0xFFFFFFFFu << (shift + 8));
        for (int i = t; i < 4096; i += 256) {
            unsigned ky = keys[i];
            if ((ky & pmask) == prefix) atomicAdd(&hist[(ky >> shift) & 255u], 1u);
        }
        __syncthreads();
        if (t == 0) {
            unsigned wv = want;
            int bsel = 0;
            for (int bb = 255; bb >= 0; --bb) {
                unsigned c = hist[bb];
                if (c >= wv) { bsel = bb; break; }
                wv -= c;
            }
            bcast[0] = (unsigned)bsel; bcast[1] = wv;
        }
        __syncthreads();
        prefix = prefix | (bcast[0] << shift);
        want = bcast[1];
        __syncthreads();
    }
    unsigned fb = (prefix & 0x80000000u) ? (prefix ^ 0x80000000u) : ~prefix;
    float Ta = __uint_as_float(fb);
    float Thi = Ta + DELTA, Tlo = Ta - DELTA;

    int* sel = selidx + (size_t)bh * NS_;
    int* bnd = band + (size_t)bh * BANDCAP;
    for (int i = t; i < 4096; i += 256) {
        float v = sc[i];
        if (v > Thi) {
            int p = atomicAdd(&cnt_in, 1);
            sel[p] = i;
        } else if (v >= Tlo) {
            int p = atomicAdd(&cnt_band, 1);
            if (p < BANDCAP) bnd[p] = i;
        }
    }
    __syncthreads();
    if (t == 0) {
        meta[bh * 2 + 0] = cnt_in;
        meta[bh * 2 + 1] = (cnt_band < BANDCAP) ? cnt_band : BANDCAP;
    }
}

// ---------------------------------------------------------------------------
// Kernel 4: exact fp64 band rescoring — ONE BLOCK PER BAND TOKEN (parallel).
// ---------------------------------------------------------------------------
__global__ __launch_bounds__(256) void band_exact_kernel(
    const float* __restrict__ x,
    const float* __restrict__ Wq, const float* __restrict__ Wk,
    const int* __restrict__ band, const int* __restrict__ meta,
    double* __restrict__ bscore)
{
    int j = blockIdx.x, bh = blockIdx.y;
    int NB = meta[bh * 2 + 1];
    if (j >= NB) return;
    int b = bh >> 4, h = bh & 15;
    int s = band[(size_t)bh * BANDCAP + j];
    int t = threadIdx.x;

    __shared__ float xs[1024];
    __shared__ double part[256];
    *(float4*)&xs[t * 4] = *(const float4*)(x + (size_t)(b * S_ + s) * K_ + t * 4);
    __syncthreads();

    int d = t & 63, role = (t >> 6) & 1, half = t >> 7;
    const float* wrow = (role ? Wk : Wq) + (size_t)(h * 64 + d) * K_ + half * 512;
    const float* xloc = xs + half * 512;
    double a0 = 0, a1 = 0, a2 = 0, a3 = 0;
    for (int k4 = 0; k4 < 128; ++k4) {
        float4 wv = *(const float4*)(wrow + k4 * 4);
        float4 xv = *(const float4*)(xloc + k4 * 4);
        a0 += (double)xv.x * wv.x; a1 += (double)xv.y * wv.y;
        a2 += (double)xv.z * wv.z; a3 += (double)xv.w * wv.w;
    }
    part[t] = (a0 + a1) + (a2 + a3);
    __syncthreads();
    if (t < 64) {
        double qd = part[t] + part[t + 128];
        double kd = part[t + 64] + part[t + 192];
        double p = qd * kd;
#pragma unroll
        for (int m = 32; m; m >>= 1) p += __shfl_xor(p, m, 64);
        if (t == 0) bscore[(size_t)bh * BANDCAP + j] = p;
    }
}

// Kernel 5: rank band tokens (ties -> lower index), fill selidx positions.
__global__ __launch_bounds__(128) void band_rank_kernel(
    const double* __restrict__ bscore, const int* __restrict__ band,
    const int* __restrict__ meta, int* __restrict__ selidx)
{
    __shared__ double sc[BANDCAP];
    __shared__ int bi[BANDCAP];
    int bh = blockIdx.x, t = threadIdx.x;
    int cnt_in = meta[bh * 2 + 0], NB = meta[bh * 2 + 1];
    int need = NS_ - cnt_in;
    if (t < NB) {
        sc[t] = bscore[(size_t)bh * BANDCAP + t];
        bi[t] = band[(size_t)bh * BANDCAP + t];
    }
    __syncthreads();
    if (t < NB) {
        double mine = sc[t]; int myi = bi[t]; int r = 0;
        for (int j2 = 0; j2 < NB; ++j2)
            r += (sc[j2] > mine) || (sc[j2] == mine && bi[j2] < myi);
        if (r < need) selidx[(size_t)bh * NS_ + cnt_in + r] = myi;
    }
}

// ---------------------------------------------------------------------------
// Kernel 6: partial KV reductions, LDS-staged coalesced. 16 chunks x 256 toks.
// ---------------------------------------------------------------------------
__global__ __launch_bounds__(256) void kv_partial_kernel(
    const float* __restrict__ k32, const ushort* __restrict__ v16,
    float* __restrict__ kvp)
{
    __shared__ float kls[16 * 64];
    __shared__ float vls[16 * 64];
    int ch = blockIdx.x;   // 0..15
    int bh = blockIdx.y;   // 0..63
    int b = bh >> 4, h = bh & 15;
    int t = threadIdx.x;
    int d0 = (t >> 4) * 4, e0 = (t & 15) * 4;
    int lr = t >> 4, lc = (t & 15) * 4;   // staging map: row, col4

    float accC[4][4] = {}, accS[4][4] = {};
    const float* kbase = k32 + (size_t)b * S_ * E_ + h * 64;
    const ushort* vbase = v16 + (size_t)b * S_ * E_ + h * 64;
    int s0 = ch * 256;

    for (int g = 0; g < 16; ++g) {
        int srow = s0 + g * 16 + lr;
        float4 kf = *(const float4*)(kbase + (size_t)srow * E_ + lc);
        ushort4 vu = *(const ushort4*)(vbase + (size_t)srow * E_ + lc);
        __syncthreads();
        *(float4*)&kls[lr * 64 + lc] = kf;
        float4 vf = { bf16_to_f(vu.x), bf16_to_f(vu.y),
                      bf16_to_f(vu.z), bf16_to_f(vu.w) };
        *(float4*)&vls[lr * 64 + lc] = vf;
        __syncthreads();
#pragma unroll 4
        for (int si = 0; si < 16; ++si) {
            int s = s0 + g * 16 + si;
            float th = (float)s * THSTEP;
            float cw = __cosf(th), sw = __sinf(th);
            float4 kf2 = *(const float4*)&kls[si * 64 + d0];
            float4 vf2 = *(const float4*)&vls[si * 64 + e0];
            float kr[4] = { fmaxf(kf2.x, 0.f), fmaxf(kf2.y, 0.f),
                            fmaxf(kf2.z, 0.f), fmaxf(kf2.w, 0.f) };
            float vv[4] = { vf2.x, vf2.y, vf2.z, vf2.w };
            float kc[4], ksn[4];
#pragma unroll
            for (int i = 0; i < 4; i++) { kc[i] = kr[i] * cw; ksn[i] = kr[i] * sw; }
#pragma unroll
            for (int i = 0; i < 4; i++)
#pragma unroll
                for (int jj = 0; jj < 4; jj++) {
                    accC[i][jj] += kc[i] * vv[jj];
                    accS[i][jj] += ksn[i] * vv[jj];
                }
        }
    }
    float* pc = kvp + ((size_t)(bh * 16 + ch) * 2) * 4096;
    float* ps = pc + 4096;
#pragma unroll
    for (int i = 0; i < 4; i++)
#pragma unroll
        for (int jj = 0; jj < 4; jj++) {
            pc[(d0 + i) * 64 + (e0 + jj)] = accC[i][jj];
            ps[(d0 + i) * 64 + (e0 + jj)] = accS[i][jj];
        }
}

// Kernel 7: reduce the 16 partials -> kv[bh][{cos,sin}][64][64]
__global__ __launch_bounds__(256) void kv_reduce_kernel(
    const float* __restrict__ kvp, float* __restrict__ kv)
{
    int i = blockIdx.x * 256 + threadIdx.x;   // 0 .. 64*2*4096-1
    if (i >= 64 * 2 * 4096) return;
    int bh = i >> 13;
    int rem = i & 8191;
    const float* p = kvp + (size_t)bh * 16 * 8192 + rem;
    float a = 0.f;
#pragma unroll
    for (int c = 0; c < 16; c++) a += p[c * 8192];
    kv[i] = a;
}

// ---------------------------------------------------------------------------
// Kernel 8: sampled = qs_cos @ kv_cos + qs_sin @ kv_sin, scattered to out rows
// ---------------------------------------------------------------------------
__global__ __launch_bounds__(256) void sampled_kernel(
    const float* __restrict__ q32, const int* __restrict__ selidx,
    const float* __restrict__ kv, float* __restrict__ out)
{
    __shared__ float kvc[4096];
    __shared__ float kvs[4096];
    int bh = blockIdx.y;
    int b = bh >> 4, h = bh & 15;
    int t = threadIdx.x;
    const float* kvsrc = kv + (size_t)bh * 8192;
    for (int i = t; i < 4096; i += 256) {
        kvc[i] = kvsrc[i];
        kvs[i] = kvsrc[4096 + i];
    }
    __syncthreads();

    int n = blockIdx.x * 256 + t;
    int s = selidx[(size_t)bh * NS_ + n];
    const float* qr = q32 + (size_t)(b * S_ + s) * E_ + h * 64;
    float th = (float)s * THSTEP;
    float cw = __cosf(th), sw = __sinf(th);

    float acc[64];
#pragma unroll
    for (int e = 0; e < 64; e++) acc[e] = 0.f;

    for (int d = 0; d < 64; ++d) {
        float qd = fmaxf(qr[d], 0.f);
        float a = qd * cw, bb = qd * sw;
        const float4* pc4 = (const float4*)&kvc[d * 64];
        const float4* ps4 = (const float4*)&kvs[d * 64];
#pragma unroll
        for (int e4 = 0; e4 < 16; e4++) {
            float4 c4 = pc4[e4], s4 = ps4[e4];
            acc[e4 * 4 + 0] += a * c4.x + bb * s4.x;
            acc[e4 * 4 + 1] += a * c4.y + bb * s4.y;
            acc[e4 * 4 + 2] += a * c4.z + bb * s4.z;
            acc[e4 * 4 + 3] += a * c4.w + bb * s4.w;
        }
    }
    float* orow = out + (size_t)(b * S_ + s) * E_ + h * 64;
#pragma unroll
    for (int e = 0; e < 64; e++) orow[e] = acc[e];
}

__global__ void zero_kernel(uint4* __restrict__ p, int n16)
{
    int stride = gridDim.x * blockDim.x;
    for (int i = blockIdx.x * blockDim.x + threadIdx.x; i < n16; i += stride)
        p[i] = make_uint4(0u, 0u, 0u, 0u);
}

extern "C" void kernel_launch(void* const* d_in, const int* in_sizes, int n_in,
                              void* d_out, int out_size, void* d_ws, size_t ws_size,
                              hipStream_t stream)
{
    const float* x  = (const float*)d_in[0];
    const float* Wq = (const float*)d_in[1];
    const float* bq = (const float*)d_in[2];
    const float* Wk = (const float*)d_in[3];
    const float* bk = (const float*)d_in[4];
    const float* Wv = (const float*)d_in[5];
    const float* bv = (const float*)d_in[6];

    char* ws = (char*)d_ws;
    ushort* xh     = (ushort*)(ws);                   // 33,554,432 B
    float*  kvp    = (float*)(ws);                    // aliases xh (dead after GEMM)
    float*  q32    = (float*)(ws + 33554432);         // 67,108,864 B
    float*  k32    = (float*)(ws + 100663296);        // 67,108,864 B
    ushort* v16    = (ushort*)(ws + 167772160);       // 33,554,432 B
    ushort* Wqh    = (ushort*)(ws + 201326592);       //  2,097,152 B
    ushort* Wql    = (ushort*)(ws + 203423744);
    ushort* Wkh    = (ushort*)(ws + 205520896);
    ushort* Wkl    = (ushort*)(ws + 207618048);
    ushort* Wvh    = (ushort*)(ws + 209715200);
    float*  scores = (float*)(ws + 211812352);        //  1,048,576 B
    int*    selidx = (int*)(ws + 212860928);          //    262,144 B
    int*    band   = (int*)(ws + 213123072);          //     24,576 B
    double* bscore = (double*)(ws + 213147648);       //     49,152 B
    int*    meta   = (int*)(ws + 213196800);          //        512 B
    float*  kv     = (float*)(ws + 213197312);        //  2,097,152 B (end ~205.3 MiB)
    float*  out    = (float*)d_out;

    hipLaunchKernelGGL(zero_kernel, dim3(2048), dim3(256), 0, stream,
                       (uint4*)out, (int)((size_t)M_ * E_ * 4 / 16));
    hipLaunchKernelGGL(split_x_kernel, dim3((M_ * K_) / 1024), dim3(256), 0, stream,
                       x, xh);
    hipLaunchKernelGGL(split_w_kernel, dim3((E_ * E_) / 1024), dim3(256), 0, stream,
                       Wq, Wk, Wv, Wqh, Wql, Wkh, Wkl, Wvh);
    hipLaunchKernelGGL(qkv_gemm, dim3(8, 128, 3), dim3(256), 0, stream,
                       xh, Wqh, Wql, Wkh, Wkl, Wvh, bq, bk, bv, q32, k32, v16);
    hipLaunchKernelGGL(scores_kernel, dim3((B_ * H_ * S_) / 4), dim3(256), 0, stream,
                       q32, k32, scores);
    hipLaunchKernelGGL(band_select_kernel, dim3(B_ * H_), dim3(256), 0, stream,
                       scores, selidx, band, meta);
    hipLaunchKernelGGL(band_exact_kernel, dim3(BANDCAP, B_ * H_), dim3(256), 0, stream,
                       x, Wq, Wk, band, meta, bscore);
    hipLaunchKernelGGL(band_rank_kernel, dim3(B_ * H_), dim3(128), 0, stream,
                       bscore, band, meta, selidx);
    hipLaunchKernelGGL(kv_partial_kernel, dim3(16, 64), dim3(256), 0, stream,
                       k32, v16, kvp);
    hipLaunchKernelGGL(kv_reduce_kernel, dim3(2048), dim3(256), 0, stream,
                       kvp, kv);
    hipLaunchKernelGGL(sampled_kernel, dim3(NS_ / 256, B_ * H_), dim3(256), 0, stream,
                       q32, selidx, kv, out);
}

// Round 5
// 909.638 us; speedup vs baseline: 1.9120x; 1.5382x over previous
//
#include <hip/hip_runtime.h>
#include <hip/hip_bf16.h>

#define B_ 4
#define S_ 4096
#define E_ 1024
#define H_ 16
#define D_ 64
#define NS_ 1024
#define M_ (B_*S_)
#define K_ E_
#define DELTA 0.12f
#define BANDCAP 96

typedef __attribute__((ext_vector_type(8))) short bf16x8;
typedef __attribute__((ext_vector_type(4))) float floatx4;

#define THSTEP 0.00038349519697141023f  /* (pi/2)/4096 */

__device__ inline float bf16_to_f(unsigned short u) {
    return __uint_as_float(((unsigned)u) << 16);
}
__device__ inline unsigned short f_to_bf16(float f) {
    unsigned u = __float_as_uint(f);
    unsigned r = (u + 0x7FFFu + ((u >> 16) & 1u)) >> 16;  // RNE
    return (unsigned short)r;
}

// ---------------------------------------------------------------------------
// Split pass 1: x (fp32) -> xh (bf16 round)
// ---------------------------------------------------------------------------
__global__ __launch_bounds__(256) void split_x_kernel(
    const float* __restrict__ x, ushort* __restrict__ xh)
{
    int i = blockIdx.x * 256 + threadIdx.x;          // over float4s, exact grid
    float4 v = ((const float4*)x)[i];
    ushort4 hh;
    hh.x = f_to_bf16(v.x); hh.y = f_to_bf16(v.y);
    hh.z = f_to_bf16(v.z); hh.w = f_to_bf16(v.w);
    ((ushort4*)xh)[i] = hh;
}

// Split pass 2: Wq,Wk -> hi+lo bf16; Wv -> hi only
__global__ __launch_bounds__(256) void split_w_kernel(
    const float* __restrict__ Wq, const float* __restrict__ Wk,
    const float* __restrict__ Wv,
    ushort* __restrict__ Wqh, ushort* __restrict__ Wql,
    ushort* __restrict__ Wkh, ushort* __restrict__ Wkl,
    ushort* __restrict__ Wvh)
{
    int i = blockIdx.x * 256 + threadIdx.x;          // over float4s, exact grid
    float4 q = ((const float4*)Wq)[i];
    float4 k = ((const float4*)Wk)[i];
    float4 v = ((const float4*)Wv)[i];
    ushort4 h, l;
    h.x=f_to_bf16(q.x); l.x=f_to_bf16(q.x-bf16_to_f(h.x));
    h.y=f_to_bf16(q.y); l.y=f_to_bf16(q.y-bf16_to_f(h.y));
    h.z=f_to_bf16(q.z); l.z=f_to_bf16(q.z-bf16_to_f(h.z));
    h.w=f_to_bf16(q.w); l.w=f_to_bf16(q.w-bf16_to_f(h.w));
    ((ushort4*)Wqh)[i]=h; ((ushort4*)Wql)[i]=l;
    h.x=f_to_bf16(k.x); l.x=f_to_bf16(k.x-bf16_to_f(h.x));
    h.y=f_to_bf16(k.y); l.y=f_to_bf16(k.y-bf16_to_f(h.y));
    h.z=f_to_bf16(k.z); l.z=f_to_bf16(k.z-bf16_to_f(h.z));
    h.w=f_to_bf16(k.w); l.w=f_to_bf16(k.w-bf16_to_f(h.w));
    ((ushort4*)Wkh)[i]=h; ((ushort4*)Wkl)[i]=l;
    h.x=f_to_bf16(v.x); h.y=f_to_bf16(v.y);
    h.z=f_to_bf16(v.z); h.w=f_to_bf16(v.w);
    ((ushort4*)Wvh)[i]=h;
}

// ---------------------------------------------------------------------------
// Kernel 1: QKV GEMM, pure bf16.  Direct load->LDS staging (NO cross-barrier
// register carry — R4's carry spilled: WRITE_SIZE 164MB->2.46GB).
// q,k: K-extent 2048 (A=xh both passes, B = Wh then Wl)  -> fp32 out
// v:   K-extent 1024 (hh only)                           -> bf16 out
// 128x128 tile, 4 waves, BK=64, XOR-swizzled LDS chunks, ds_read_b128 frags.
// ---------------------------------------------------------------------------
__global__ __launch_bounds__(256) void qkv_gemm(
    const ushort* __restrict__ xh,
    const ushort* __restrict__ Wqh, const ushort* __restrict__ Wql,
    const ushort* __restrict__ Wkh, const ushort* __restrict__ Wkl,
    const ushort* __restrict__ Wvh,
    const float* __restrict__ bq, const float* __restrict__ bk,
    const float* __restrict__ bv,
    float* __restrict__ q32, float* __restrict__ k32, ushort* __restrict__ v16)
{
    __shared__ __align__(16) ushort As[128 * 64];
    __shared__ __align__(16) ushort Bs[128 * 64];

    const int w = blockIdx.z;
    const ushort* Bhp = (w == 0) ? Wqh : (w == 1) ? Wkh : Wvh;
    const ushort* Blp = (w == 0) ? Wql : Wkl;      // unused when w==2
    const float* bias = (w == 0) ? bq : (w == 1) ? bk : bv;
    const int NK = (w < 2) ? 32 : 16;

    const int m0 = blockIdx.y * 128;
    const int n0 = blockIdx.x * 128;
    const int t = threadIdx.x;
    const int wave = t >> 6, lane = t & 63;
    const int wm = (wave >> 1) * 64, wn = (wave & 1) * 64;
    const int m16 = lane & 15, quad = lane >> 4;

    floatx4 acc[4][4];
#pragma unroll
    for (int i = 0; i < 4; i++)
#pragma unroll
        for (int j = 0; j < 4; j++) acc[i][j] = (floatx4){0.f, 0.f, 0.f, 0.f};

    // per-thread constant staging offsets (32-bit element offsets)
    int aoff[4], boff[4], lofs[4];
#pragma unroll
    for (int i = 0; i < 4; i++) {
        int slot = i * 256 + t;
        int r = slot >> 3, c = slot & 7, g = c ^ (r & 7);
        aoff[i] = (m0 + r) * K_ + g * 8;
        boff[i] = (n0 + r) * K_ + g * 8;
        lofs[i] = slot * 8;
    }

    for (int ks = 0; ks < NK; ++ks) {
        const int kcol = (ks & 15) * 64;
        const ushort* Bsrc = (ks >= 16) ? Blp : Bhp;
        // stage: load -> immediately store to LDS (no value lives across a barrier)
#pragma unroll
        for (int i = 0; i < 4; i++) {
            uint4 av = *(const uint4*)(xh + aoff[i] + kcol);
            uint4 bv4 = *(const uint4*)(Bsrc + boff[i] + kcol);
            *(uint4*)&As[lofs[i]] = av;
            *(uint4*)&Bs[lofs[i]] = bv4;
        }
        __syncthreads();

#pragma unroll
        for (int kk = 0; kk < 2; ++kk) {
            bf16x8 af[4], bfr[4];
            const int g = kk * 4 + quad;
#pragma unroll
            for (int mt = 0; mt < 4; ++mt) {
                int r = wm + mt * 16 + m16;
                af[mt] = *(const bf16x8*)&As[(r * 8 + (g ^ (r & 7))) * 8];
                int r2 = wn + mt * 16 + m16;
                bfr[mt] = *(const bf16x8*)&Bs[(r2 * 8 + (g ^ (r2 & 7))) * 8];
            }
#pragma unroll
            for (int mt = 0; mt < 4; ++mt)
#pragma unroll
                for (int nt = 0; nt < 4; ++nt)
                    acc[mt][nt] = __builtin_amdgcn_mfma_f32_16x16x32_bf16(
                        af[mt], bfr[nt], acc[mt][nt], 0, 0, 0);
        }
        __syncthreads();
    }

    // epilogue:  C row = quad*4+reg, col = lane&15  [m89/m91 verified layout]
    float biasv[4];
#pragma unroll
    for (int nt = 0; nt < 4; nt++)
        biasv[nt] = bias[n0 + wn + nt * 16 + m16];

    if (w < 2) {
        float* dst = (w == 0) ? q32 : k32;
#pragma unroll
        for (int mt = 0; mt < 4; ++mt)
#pragma unroll
            for (int nt = 0; nt < 4; ++nt) {
                int colg = n0 + wn + nt * 16 + m16;
#pragma unroll
                for (int reg = 0; reg < 4; ++reg) {
                    int rowg = m0 + wm + mt * 16 + quad * 4 + reg;
                    dst[(size_t)rowg * E_ + colg] = acc[mt][nt][reg] + biasv[nt];
                }
            }
    } else {
#pragma unroll
        for (int mt = 0; mt < 4; ++mt)
#pragma unroll
            for (int nt = 0; nt < 4; ++nt) {
                int colg = n0 + wn + nt * 16 + m16;
#pragma unroll
                for (int reg = 0; reg < 4; ++reg) {
                    int rowg = m0 + wm + mt * 16 + quad * 4 + reg;
                    v16[(size_t)rowg * E_ + colg] = f_to_bf16(acc[mt][nt][reg] + biasv[nt]);
                }
            }
    }
}

// ---------------------------------------------------------------------------
// Kernel 2: approx scores[b,h,s] = sum_d q*k (raw q,k fp32). one wave/token
// ---------------------------------------------------------------------------
__global__ __launch_bounds__(256) void scores_kernel(
    const float* __restrict__ q32, const float* __restrict__ k32,
    float* __restrict__ scores)
{
    int wid = blockIdx.x * 4 + (threadIdx.x >> 6);
    int lane = threadIdx.x & 63;
    int s = wid & (S_ - 1);
    int bh = wid >> 12;
    int b = bh >> 4, h = bh & 15;
    size_t addr = (size_t)(b * S_ + s) * E_ + h * 64 + lane;
    float p = q32[addr] * k32[addr];
#pragma unroll
    for (int m = 32; m; m >>= 1) p += __shfl_xor(p, m, 64);
    if (lane == 0) scores[wid] = p;
}

// ---------------------------------------------------------------------------
// Kernel 3: radix-select 1024th approx score T_a; classify into definite-in
// (> T_a+DELTA) and band (|score-T_a| <= DELTA).
// ---------------------------------------------------------------------------
__global__ __launch_bounds__(256) void band_select_kernel(
    const float* __restrict__ scores, int* __restrict__ selidx,
    int* __restrict__ band, int* __restrict__ meta)
{
    __shared__ unsigned keys[4096];
    __shared__ unsigned hist[256];
    __shared__ unsigned bcast[2];
    __shared__ int cnt_in, cnt_band;

    int bh = blockIdx.x;
    int t = threadIdx.x;
    const float* sc = scores + (size_t)bh * S_;

    for (int i = t; i < 4096; i += 256) {
        unsigned u = __float_as_uint(sc[i]);
        u = (u & 0x80000000u) ? ~u : (u | 0x80000000u);
        keys[i] = u;
    }
    if (t == 0) { cnt_in = 0; cnt_band = 0; }
    __syncthreads();

    unsigned prefix = 0, want = NS_;
    for (int shift = 24; shift >= 0; shift -= 8) {
        hist[t] = 0;
        __syncthreads();
        unsigned pmask = (shift == 24) ? 0u : (0xFFFFFFFFu << (shift + 8));
        for (int i = t; i < 4096; i += 256) {
            unsigned ky = keys[i];
            if ((ky & pmask) == prefix) atomicAdd(&hist[(ky >> shift) & 255u], 1u);
        }
        __syncthreads();
        if (t == 0) {
            unsigned wv = want;
            int bsel = 0;
            for (int bb = 255; bb >= 0; --bb) {
                unsigned c = hist[bb];
                if (c >= wv) { bsel = bb; break; }
                wv -= c;
            }
            bcast[0] = (unsigned)bsel; bcast[1] = wv;
        }
        __syncthreads();
        prefix = prefix | (bcast[0] << shift);
        want = bcast[1];
        __syncthreads();
    }
    unsigned fb = (prefix & 0x80000000u) ? (prefix ^ 0x80000000u) : ~prefix;
    float Ta = __uint_as_float(fb);
    float Thi = Ta + DELTA, Tlo = Ta - DELTA;

    int* sel = selidx + (size_t)bh * NS_;
    int* bnd = band + (size_t)bh * BANDCAP;
    for (int i = t; i < 4096; i += 256) {
        float v = sc[i];
        if (v > Thi) {
            int p = atomicAdd(&cnt_in, 1);
            sel[p] = i;
        } else if (v >= Tlo) {
            int p = atomicAdd(&cnt_band, 1);
            if (p < BANDCAP) bnd[p] = i;
        }
    }
    __syncthreads();
    if (t == 0) {
        meta[bh * 2 + 0] = cnt_in;
        meta[bh * 2 + 1] = (cnt_band < BANDCAP) ? cnt_band : BANDCAP;
    }
}

// ---------------------------------------------------------------------------
// Kernel 4: exact fp64 band rescoring — one block per band token.
// ---------------------------------------------------------------------------
__global__ __launch_bounds__(256) void band_exact_kernel(
    const float* __restrict__ x,
    const float* __restrict__ Wq, const float* __restrict__ Wk,
    const int* __restrict__ band, const int* __restrict__ meta,
    double* __restrict__ bscore)
{
    int j = blockIdx.x, bh = blockIdx.y;
    int NB = meta[bh * 2 + 1];
    if (j >= NB) return;
    int b = bh >> 4, h = bh & 15;
    int s = band[(size_t)bh * BANDCAP + j];
    int t = threadIdx.x;

    __shared__ float xs[1024];
    __shared__ double part[256];
    *(float4*)&xs[t * 4] = *(const float4*)(x + (size_t)(b * S_ + s) * K_ + t * 4);
    __syncthreads();

    int d = t & 63, role = (t >> 6) & 1, half = t >> 7;
    const float* wrow = (role ? Wk : Wq) + (size_t)(h * 64 + d) * K_ + half * 512;
    const float* xloc = xs + half * 512;
    double a0 = 0, a1 = 0, a2 = 0, a3 = 0;
    for (int k4 = 0; k4 < 128; ++k4) {
        float4 wv = *(const float4*)(wrow + k4 * 4);
        float4 xv = *(const float4*)(xloc + k4 * 4);
        a0 += (double)xv.x * wv.x; a1 += (double)xv.y * wv.y;
        a2 += (double)xv.z * wv.z; a3 += (double)xv.w * wv.w;
    }
    part[t] = (a0 + a1) + (a2 + a3);
    __syncthreads();
    if (t < 64) {
        double qd = part[t] + part[t + 128];
        double kd = part[t + 64] + part[t + 192];
        double p = qd * kd;
#pragma unroll
        for (int m = 32; m; m >>= 1) p += __shfl_xor(p, m, 64);
        if (t == 0) bscore[(size_t)bh * BANDCAP + j] = p;
    }
}

// Kernel 5: rank band tokens (ties -> lower index), fill selidx positions.
__global__ __launch_bounds__(128) void band_rank_kernel(
    const double* __restrict__ bscore, const int* __restrict__ band,
    const int* __restrict__ meta, int* __restrict__ selidx)
{
    __shared__ double sc[BANDCAP];
    __shared__ int bi[BANDCAP];
    int bh = blockIdx.x, t = threadIdx.x;
    int cnt_in = meta[bh * 2 + 0], NB = meta[bh * 2 + 1];
    int need = NS_ - cnt_in;
    if (t < NB) {
        sc[t] = bscore[(size_t)bh * BANDCAP + t];
        bi[t] = band[(size_t)bh * BANDCAP + t];
    }
    __syncthreads();
    if (t < NB) {
        double mine = sc[t]; int myi = bi[t]; int r = 0;
        for (int j2 = 0; j2 < NB; ++j2)
            r += (sc[j2] > mine) || (sc[j2] == mine && bi[j2] < myi);
        if (r < need) selidx[(size_t)bh * NS_ + cnt_in + r] = myi;
    }
}

// ---------------------------------------------------------------------------
// Kernel 6: partial KV reductions, LDS-staged coalesced. 16 chunks x 256 toks.
// ---------------------------------------------------------------------------
__global__ __launch_bounds__(256) void kv_partial_kernel(
    const float* __restrict__ k32, const ushort* __restrict__ v16,
    float* __restrict__ kvp)
{
    __shared__ float kls[16 * 64];
    __shared__ float vls[16 * 64];
    int ch = blockIdx.x;   // 0..15
    int bh = blockIdx.y;   // 0..63
    int b = bh >> 4, h = bh & 15;
    int t = threadIdx.x;
    int d0 = (t >> 4) * 4, e0 = (t & 15) * 4;
    int lr = t >> 4, lc = (t & 15) * 4;   // staging map: row, col4

    float accC[4][4] = {}, accS[4][4] = {};
    const float* kbase = k32 + (size_t)b * S_ * E_ + h * 64;
    const ushort* vbase = v16 + (size_t)b * S_ * E_ + h * 64;
    int s0 = ch * 256;

    for (int g = 0; g < 16; ++g) {
        int srow = s0 + g * 16 + lr;
        float4 kf = *(const float4*)(kbase + (size_t)srow * E_ + lc);
        ushort4 vu = *(const ushort4*)(vbase + (size_t)srow * E_ + lc);
        __syncthreads();
        *(float4*)&kls[lr * 64 + lc] = kf;
        float4 vf = { bf16_to_f(vu.x), bf16_to_f(vu.y),
                      bf16_to_f(vu.z), bf16_to_f(vu.w) };
        *(float4*)&vls[lr * 64 + lc] = vf;
        __syncthreads();
#pragma unroll 4
        for (int si = 0; si < 16; ++si) {
            int s = s0 + g * 16 + si;
            float th = (float)s * THSTEP;
            float cw = __cosf(th), sw = __sinf(th);
            float4 kf2 = *(const float4*)&kls[si * 64 + d0];
            float4 vf2 = *(const float4*)&vls[si * 64 + e0];
            float kr[4] = { fmaxf(kf2.x, 0.f), fmaxf(kf2.y, 0.f),
                            fmaxf(kf2.z, 0.f), fmaxf(kf2.w, 0.f) };
            float vv[4] = { vf2.x, vf2.y, vf2.z, vf2.w };
            float kc[4], ksn[4];
#pragma unroll
            for (int i = 0; i < 4; i++) { kc[i] = kr[i] * cw; ksn[i] = kr[i] * sw; }
#pragma unroll
            for (int i = 0; i < 4; i++)
#pragma unroll
                for (int jj = 0; jj < 4; jj++) {
                    accC[i][jj] += kc[i] * vv[jj];
                    accS[i][jj] += ksn[i] * vv[jj];
                }
        }
    }
    float* pc = kvp + ((size_t)(bh * 16 + ch) * 2) * 4096;
    float* ps = pc + 4096;
#pragma unroll
    for (int i = 0; i < 4; i++)
#pragma unroll
        for (int jj = 0; jj < 4; jj++) {
            pc[(d0 + i) * 64 + (e0 + jj)] = accC[i][jj];
            ps[(d0 + i) * 64 + (e0 + jj)] = accS[i][jj];
        }
}

// Kernel 7: reduce the 16 partials -> kv[bh][{cos,sin}][64][64]
__global__ __launch_bounds__(256) void kv_reduce_kernel(
    const float* __restrict__ kvp, float* __restrict__ kv)
{
    int i = blockIdx.x * 256 + threadIdx.x;   // 0 .. 64*2*4096-1
    if (i >= 64 * 2 * 4096) return;
    int bh = i >> 13;
    int rem = i & 8191;
    const float* p = kvp + (size_t)bh * 16 * 8192 + rem;
    float a = 0.f;
#pragma unroll
    for (int c = 0; c < 16; c++) a += p[c * 8192];
    kv[i] = a;
}

// ---------------------------------------------------------------------------
// Kernel 8: sampled = qs_cos @ kv_cos + qs_sin @ kv_sin, scattered to out rows
// ---------------------------------------------------------------------------
__global__ __launch_bounds__(256) void sampled_kernel(
    const float* __restrict__ q32, const int* __restrict__ selidx,
    const float* __restrict__ kv, float* __restrict__ out)
{
    __shared__ float kvc[4096];
    __shared__ float kvs[4096];
    int bh = blockIdx.y;
    int b = bh >> 4, h = bh & 15;
    int t = threadIdx.x;
    const float* kvsrc = kv + (size_t)bh * 8192;
    for (int i = t; i < 4096; i += 256) {
        kvc[i] = kvsrc[i];
        kvs[i] = kvsrc[4096 + i];
    }
    __syncthreads();

    int n = blockIdx.x * 256 + t;
    int s = selidx[(size_t)bh * NS_ + n];
    const float* qr = q32 + (size_t)(b * S_ + s) * E_ + h * 64;
    float th = (float)s * THSTEP;
    float cw = __cosf(th), sw = __sinf(th);

    float acc[64];
#pragma unroll
    for (int e = 0; e < 64; e++) acc[e] = 0.f;

    for (int d = 0; d < 64; ++d) {
        float qd = fmaxf(qr[d], 0.f);
        float a = qd * cw, bb = qd * sw;
        const float4* pc4 = (const float4*)&kvc[d * 64];
        const float4* ps4 = (const float4*)&kvs[d * 64];
#pragma unroll
        for (int e4 = 0; e4 < 16; e4++) {
            float4 c4 = pc4[e4], s4 = ps4[e4];
            acc[e4 * 4 + 0] += a * c4.x + bb * s4.x;
            acc[e4 * 4 + 1] += a * c4.y + bb * s4.y;
            acc[e4 * 4 + 2] += a * c4.z + bb * s4.z;
            acc[e4 * 4 + 3] += a * c4.w + bb * s4.w;
        }
    }
    float* orow = out + (size_t)(b * S_ + s) * E_ + h * 64;
#pragma unroll
    for (int e = 0; e < 64; e++) orow[e] = acc[e];
}

__global__ void zero_kernel(uint4* __restrict__ p, int n16)
{
    int stride = gridDim.x * blockDim.x;
    for (int i = blockIdx.x * blockDim.x + threadIdx.x; i < n16; i += stride)
        p[i] = make_uint4(0u, 0u, 0u, 0u);
}

extern "C" void kernel_launch(void* const* d_in, const int* in_sizes, int n_in,
                              void* d_out, int out_size, void* d_ws, size_t ws_size,
                              hipStream_t stream)
{
    const float* x  = (const float*)d_in[0];
    const float* Wq = (const float*)d_in[1];
    const float* bq = (const float*)d_in[2];
    const float* Wk = (const float*)d_in[3];
    const float* bk = (const float*)d_in[4];
    const float* Wv = (const float*)d_in[5];
    const float* bv = (const float*)d_in[6];

    char* ws = (char*)d_ws;
    ushort* xh     = (ushort*)(ws);                   // 33,554,432 B
    float*  kvp    = (float*)(ws);                    // aliases xh (dead after GEMM)
    float*  q32    = (float*)(ws + 33554432);         // 67,108,864 B
    float*  k32    = (float*)(ws + 100663296);        // 67,108,864 B
    ushort* v16    = (ushort*)(ws + 167772160);       // 33,554,432 B
    ushort* Wqh    = (ushort*)(ws + 201326592);       //  2,097,152 B
    ushort* Wql    = (ushort*)(ws + 203423744);
    ushort* Wkh    = (ushort*)(ws + 205520896);
    ushort* Wkl    = (ushort*)(ws + 207618048);
    ushort* Wvh    = (ushort*)(ws + 209715200);
    float*  scores = (float*)(ws + 211812352);        //  1,048,576 B
    int*    selidx = (int*)(ws + 212860928);          //    262,144 B
    int*    band   = (int*)(ws + 213123072);          //     24,576 B
    double* bscore = (double*)(ws + 213147648);       //     49,152 B
    int*    meta   = (int*)(ws + 213196800);          //        512 B
    float*  kv     = (float*)(ws + 213197312);        //  2,097,152 B (end ~205.3 MiB)
    float*  out    = (float*)d_out;

    hipLaunchKernelGGL(zero_kernel, dim3(2048), dim3(256), 0, stream,
                       (uint4*)out, (int)((size_t)M_ * E_ * 4 / 16));
    hipLaunchKernelGGL(split_x_kernel, dim3((M_ * K_) / 1024), dim3(256), 0, stream,
                       x, xh);
    hipLaunchKernelGGL(split_w_kernel, dim3((E_ * E_) / 1024), dim3(256), 0, stream,
                       Wq, Wk, Wv, Wqh, Wql, Wkh, Wkl, Wvh);
    hipLaunchKernelGGL(qkv_gemm, dim3(8, 128, 3), dim3(256), 0, stream,
                       xh, Wqh, Wql, Wkh, Wkl, Wvh, bq, bk, bv, q32, k32, v16);
    hipLaunchKernelGGL(scores_kernel, dim3((B_ * H_ * S_) / 4), dim3(256), 0, stream,
                       q32, k32, scores);
    hipLaunchKernelGGL(band_select_kernel, dim3(B_ * H_), dim3(256), 0, stream,
                       scores, selidx, band, meta);
    hipLaunchKernelGGL(band_exact_kernel, dim3(BANDCAP, B_ * H_), dim3(256), 0, stream,
                       x, Wq, Wk, band, meta, bscore);
    hipLaunchKernelGGL(band_rank_kernel, dim3(B_ * H_), dim3(128), 0, stream,
                       bscore, band, meta, selidx);
    hipLaunchKernelGGL(kv_partial_kernel, dim3(16, 64), dim3(256), 0, stream,
                       k32, v16, kvp);
    hipLaunchKernelGGL(kv_reduce_kernel, dim3(2048), dim3(256), 0, stream,
                       kvp, kv);
    hipLaunchKernelGGL(sampled_kernel, dim3(NS_ / 256, B_ * H_), dim3(256), 0, stream,
                       q32, selidx, kv, out);
}

// Round 6
// 699.001 us; speedup vs baseline: 2.4882x; 1.3013x over previous
//
#include <hip/hip_runtime.h>
#include <hip/hip_bf16.h>

#define B_ 4
#define S_ 4096
#define E_ 1024
#define H_ 16
#define D_ 64
#define NS_ 1024
#define M_ (B_*S_)
#define K_ E_
#define DELTA 0.12f
#define BANDCAP 96

typedef __attribute__((ext_vector_type(8))) short bf16x8;
typedef __attribute__((ext_vector_type(4))) float floatx4;

#define THSTEP 0.00038349519697141023f  /* (pi/2)/4096 */

__device__ inline float bf16_to_f(unsigned short u) {
    return __uint_as_float(((unsigned)u) << 16);
}
__device__ inline unsigned short f_to_bf16(float f) {
    unsigned u = __float_as_uint(f);
    unsigned r = (u + 0x7FFFu + ((u >> 16) & 1u)) >> 16;  // RNE
    return (unsigned short)r;
}

// ---------------------------------------------------------------------------
// Split pass 1: x (fp32) -> xh (bf16 round)
// ---------------------------------------------------------------------------
__global__ __launch_bounds__(256) void split_x_kernel(
    const float* __restrict__ x, ushort* __restrict__ xh)
{
    int i = blockIdx.x * 256 + threadIdx.x;          // over float4s, exact grid
    float4 v = ((const float4*)x)[i];
    ushort4 hh;
    hh.x = f_to_bf16(v.x); hh.y = f_to_bf16(v.y);
    hh.z = f_to_bf16(v.z); hh.w = f_to_bf16(v.w);
    ((ushort4*)xh)[i] = hh;
}

// Split pass 2: Wq,Wk -> hi+lo bf16; Wv -> hi only
__global__ __launch_bounds__(256) void split_w_kernel(
    const float* __restrict__ Wq, const float* __restrict__ Wk,
    const float* __restrict__ Wv,
    ushort* __restrict__ Wqh, ushort* __restrict__ Wql,
    ushort* __restrict__ Wkh, ushort* __restrict__ Wkl,
    ushort* __restrict__ Wvh)
{
    int i = blockIdx.x * 256 + threadIdx.x;          // over float4s, exact grid
    float4 q = ((const float4*)Wq)[i];
    float4 k = ((const float4*)Wk)[i];
    float4 v = ((const float4*)Wv)[i];
    ushort4 h, l;
    h.x=f_to_bf16(q.x); l.x=f_to_bf16(q.x-bf16_to_f(h.x));
    h.y=f_to_bf16(q.y); l.y=f_to_bf16(q.y-bf16_to_f(h.y));
    h.z=f_to_bf16(q.z); l.z=f_to_bf16(q.z-bf16_to_f(h.z));
    h.w=f_to_bf16(q.w); l.w=f_to_bf16(q.w-bf16_to_f(h.w));
    ((ushort4*)Wqh)[i]=h; ((ushort4*)Wql)[i]=l;
    h.x=f_to_bf16(k.x); l.x=f_to_bf16(k.x-bf16_to_f(h.x));
    h.y=f_to_bf16(k.y); l.y=f_to_bf16(k.y-bf16_to_f(h.y));
    h.z=f_to_bf16(k.z); l.z=f_to_bf16(k.z-bf16_to_f(h.z));
    h.w=f_to_bf16(k.w); l.w=f_to_bf16(k.w-bf16_to_f(h.w));
    ((ushort4*)Wkh)[i]=h; ((ushort4*)Wkl)[i]=l;
    h.x=f_to_bf16(v.x); h.y=f_to_bf16(v.y);
    h.z=f_to_bf16(v.z); h.w=f_to_bf16(v.w);
    ((ushort4*)Wvh)[i]=h;
}

// ---------------------------------------------------------------------------
// Kernel 1: QKV GEMM, pure bf16.  Direct load->LDS staging (NO cross-barrier
// register carry — R4's carry spilled: WRITE_SIZE 164MB->2.46GB).
// q,k: K-extent 2048 (A=xh both passes, B = Wh then Wl)  -> fp32 out
// v:   K-extent 1024 (hh only)                           -> bf16 out
// 128x128 tile, 4 waves, BK=64, XOR-swizzled LDS chunks, ds_read_b128 frags.
// ---------------------------------------------------------------------------
__global__ __launch_bounds__(256) void qkv_gemm(
    const ushort* __restrict__ xh,
    const ushort* __restrict__ Wqh, const ushort* __restrict__ Wql,
    const ushort* __restrict__ Wkh, const ushort* __restrict__ Wkl,
    const ushort* __restrict__ Wvh,
    const float* __restrict__ bq, const float* __restrict__ bk,
    const float* __restrict__ bv,
    float* __restrict__ q32, float* __restrict__ k32, ushort* __restrict__ v16)
{
    __shared__ __align__(16) ushort As[128 * 64];
    __shared__ __align__(16) ushort Bs[128 * 64];

    const int w = blockIdx.z;
    const ushort* Bhp = (w == 0) ? Wqh : (w == 1) ? Wkh : Wvh;
    const ushort* Blp = (w == 0) ? Wql : Wkl;      // unused when w==2
    const float* bias = (w == 0) ? bq : (w == 1) ? bk : bv;
    const int NK = (w < 2) ? 32 : 16;

    const int m0 = blockIdx.y * 128;
    const int n0 = blockIdx.x * 128;
    const int t = threadIdx.x;
    const int wave = t >> 6, lane = t & 63;
    const int wm = (wave >> 1) * 64, wn = (wave & 1) * 64;
    const int m16 = lane & 15, quad = lane >> 4;

    floatx4 acc[4][4];
#pragma unroll
    for (int i = 0; i < 4; i++)
#pragma unroll
        for (int j = 0; j < 4; j++) acc[i][j] = (floatx4){0.f, 0.f, 0.f, 0.f};

    // per-thread constant staging offsets (32-bit element offsets)
    int aoff[4], boff[4], lofs[4];
#pragma unroll
    for (int i = 0; i < 4; i++) {
        int slot = i * 256 + t;
        int r = slot >> 3, c = slot & 7, g = c ^ (r & 7);
        aoff[i] = (m0 + r) * K_ + g * 8;
        boff[i] = (n0 + r) * K_ + g * 8;
        lofs[i] = slot * 8;
    }

    for (int ks = 0; ks < NK; ++ks) {
        const int kcol = (ks & 15) * 64;
        const ushort* Bsrc = (ks >= 16) ? Blp : Bhp;
        // stage: load -> immediately store to LDS (no value lives across a barrier)
#pragma unroll
        for (int i = 0; i < 4; i++) {
            uint4 av = *(const uint4*)(xh + aoff[i] + kcol);
            uint4 bv4 = *(const uint4*)(Bsrc + boff[i] + kcol);
            *(uint4*)&As[lofs[i]] = av;
            *(uint4*)&Bs[lofs[i]] = bv4;
        }
        __syncthreads();

#pragma unroll
        for (int kk = 0; kk < 2; ++kk) {
            bf16x8 af[4], bfr[4];
            const int g = kk * 4 + quad;
#pragma unroll
            for (int mt = 0; mt < 4; ++mt) {
                int r = wm + mt * 16 + m16;
                af[mt] = *(const bf16x8*)&As[(r * 8 + (g ^ (r & 7))) * 8];
                int r2 = wn + mt * 16 + m16;
                bfr[mt] = *(const bf16x8*)&Bs[(r2 * 8 + (g ^ (r2 & 7))) * 8];
            }
#pragma unroll
            for (int mt = 0; mt < 4; ++mt)
#pragma unroll
                for (int nt = 0; nt < 4; ++nt)
                    acc[mt][nt] = __builtin_amdgcn_mfma_f32_16x16x32_bf16(
                        af[mt], bfr[nt], acc[mt][nt], 0, 0, 0);
        }
        __syncthreads();
    }

    // epilogue:  C row = quad*4+reg, col = lane&15  [m89/m91 verified layout]
    float biasv[4];
#pragma unroll
    for (int nt = 0; nt < 4; nt++)
        biasv[nt] = bias[n0 + wn + nt * 16 + m16];

    if (w < 2) {
        float* dst = (w == 0) ? q32 : k32;
#pragma unroll
        for (int mt = 0; mt < 4; ++mt)
#pragma unroll
            for (int nt = 0; nt < 4; ++nt) {
                int colg = n0 + wn + nt * 16 + m16;
#pragma unroll
                for (int reg = 0; reg < 4; ++reg) {
                    int rowg = m0 + wm + mt * 16 + quad * 4 + reg;
                    dst[(size_t)rowg * E_ + colg] = acc[mt][nt][reg] + biasv[nt];
                }
            }
    } else {
#pragma unroll
        for (int mt = 0; mt < 4; ++mt)
#pragma unroll
            for (int nt = 0; nt < 4; ++nt) {
                int colg = n0 + wn + nt * 16 + m16;
#pragma unroll
                for (int reg = 0; reg < 4; ++reg) {
                    int rowg = m0 + wm + mt * 16 + quad * 4 + reg;
                    v16[(size_t)rowg * E_ + colg] = f_to_bf16(acc[mt][nt][reg] + biasv[nt]);
                }
            }
    }
}

// ---------------------------------------------------------------------------
// Kernel 2: approx scores[b,h,s] = sum_d q*k (raw q,k fp32). one wave/token
// ---------------------------------------------------------------------------
__global__ __launch_bounds__(256) void scores_kernel(
    const float* __restrict__ q32, const float* __restrict__ k32,
    float* __restrict__ scores)
{
    int wid = blockIdx.x * 4 + (threadIdx.x >> 6);
    int lane = threadIdx.x & 63;
    int s = wid & (S_ - 1);
    int bh = wid >> 12;
    int b = bh >> 4, h = bh & 15;
    size_t addr = (size_t)(b * S_ + s) * E_ + h * 64 + lane;
    float p = q32[addr] * k32[addr];
#pragma unroll
    for (int m = 32; m; m >>= 1) p += __shfl_xor(p, m, 64);
    if (lane == 0) scores[wid] = p;
}

// ---------------------------------------------------------------------------
// Kernel 3: radix-select 1024th approx score T_a; classify into definite-in
// (> T_a+DELTA) and band (|score-T_a| <= DELTA).
// ---------------------------------------------------------------------------
__global__ __launch_bounds__(256) void band_select_kernel(
    const float* __restrict__ scores, int* __restrict__ selidx,
    int* __restrict__ band, int* __restrict__ meta)
{
    __shared__ unsigned keys[4096];
    __shared__ unsigned hist[256];
    __shared__ unsigned bcast[2];
    __shared__ int cnt_in, cnt_band;

    int bh = blockIdx.x;
    int t = threadIdx.x;
    const float* sc = scores + (size_t)bh * S_;

    for (int i = t; i < 4096; i += 256) {
        unsigned u = __float_as_uint(sc[i]);
        u = (u & 0x80000000u) ? ~u : (u | 0x80000000u);
        keys[i] = u;
    }
    if (t == 0) { cnt_in = 0; cnt_band = 0; }
    __syncthreads();

    unsigned prefix = 0, want = NS_;
    for (int shift = 24; shift >= 0; shift -= 8) {
        hist[t] = 0;
        __syncthreads();
        unsigned pmask = (shift == 24) ? 0u : (0xFFFFFFFFu << (shift + 8));
        for (int i = t; i < 4096; i += 256) {
            unsigned ky = keys[i];
            if ((ky & pmask) == prefix) atomicAdd(&hist[(ky >> shift) & 255u], 1u);
        }
        __syncthreads();
        if (t == 0) {
            unsigned wv = want;
            int bsel = 0;
            for (int bb = 255; bb >= 0; --bb) {
                unsigned c = hist[bb];
                if (c >= wv) { bsel = bb; break; }
                wv -= c;
            }
            bcast[0] = (unsigned)bsel; bcast[1] = wv;
        }
        __syncthreads();
        prefix = prefix | (bcast[0] << shift);
        want = bcast[1];
        __syncthreads();
    }
    unsigned fb = (prefix & 0x80000000u) ? (prefix ^ 0x80000000u) : ~prefix;
    float Ta = __uint_as_float(fb);
    float Thi = Ta + DELTA, Tlo = Ta - DELTA;

    int* sel = selidx + (size_t)bh * NS_;
    int* bnd = band + (size_t)bh * BANDCAP;
    for (int i = t; i < 4096; i += 256) {
        float v = sc[i];
        if (v > Thi) {
            int p = atomicAdd(&cnt_in, 1);
            sel[p] = i;
        } else if (v >= Tlo) {
            int p = atomicAdd(&cnt_band, 1);
            if (p < BANDCAP) bnd[p] = i;
        }
    }
    __syncthreads();
    if (t == 0) {
        meta[bh * 2 + 0] = cnt_in;
        meta[bh * 2 + 1] = (cnt_band < BANDCAP) ? cnt_band : BANDCAP;
    }
}

// ---------------------------------------------------------------------------
// Kernel 4: exact fp64 band rescoring — one block per band token.
// COALESCED: each wave owns one W row at a time; lane l reads float4 #(l+64p)
// of the row (contiguous 1KB/wave/instr), dots vs LDS x-row in fp64, then
// wave-reduces.  (R5 version had lane=own-row -> 64 cache lines per load.)
// ---------------------------------------------------------------------------
__global__ __launch_bounds__(256) void band_exact_kernel(
    const float* __restrict__ x,
    const float* __restrict__ Wq, const float* __restrict__ Wk,
    const int* __restrict__ band, const int* __restrict__ meta,
    double* __restrict__ bscore)
{
    int j = blockIdx.x, bh = blockIdx.y;
    int NB = meta[bh * 2 + 1];
    if (j >= NB) return;
    int b = bh >> 4, h = bh & 15;
    int s = band[(size_t)bh * BANDCAP + j];
    int t = threadIdx.x;
    int wave = t >> 6, lane = t & 63;

    __shared__ float xs[1024];
    __shared__ double qkd[128];     // [0:64)=q dots, [64:128)=k dots

    *(float4*)&xs[t * 4] = *(const float4*)(x + (size_t)(b * S_ + s) * K_ + t * 4);
    __syncthreads();

    // wave 0: Wq d=0..31 | wave 1: Wq d=32..63 | wave 2: Wk d=0..31 | wave 3: Wk d=32..63
    const float* Wbase = (wave < 2) ? Wq : Wk;
    int dbase = (wave & 1) * 32;
    int role = (wave >> 1);         // 0=q, 1=k
    const float4* xs4 = (const float4*)xs;

    for (int rr = 0; rr < 32; ++rr) {
        int d = dbase + rr;
        const float4* wrow4 = (const float4*)(Wbase + (size_t)(h * 64 + d) * K_);
        double a = 0.0;
#pragma unroll
        for (int p = 0; p < 4; ++p) {
            float4 wv = wrow4[lane + 64 * p];
            float4 xv = xs4[lane + 64 * p];
            a += (double)xv.x * wv.x + (double)xv.y * wv.y
               + (double)xv.z * wv.z + (double)xv.w * wv.w;
        }
#pragma unroll
        for (int m = 32; m; m >>= 1) a += __shfl_xor(a, m, 64);
        if (lane == 0) qkd[role * 64 + d] = a;
    }
    __syncthreads();

    if (t < 64) {
        double p = qkd[t] * qkd[64 + t];
#pragma unroll
        for (int m = 32; m; m >>= 1) p += __shfl_xor(p, m, 64);
        if (t == 0) bscore[(size_t)bh * BANDCAP + j] = p;
    }
}

// Kernel 5: rank band tokens (ties -> lower index), fill selidx positions.
__global__ __launch_bounds__(128) void band_rank_kernel(
    const double* __restrict__ bscore, const int* __restrict__ band,
    const int* __restrict__ meta, int* __restrict__ selidx)
{
    __shared__ double sc[BANDCAP];
    __shared__ int bi[BANDCAP];
    int bh = blockIdx.x, t = threadIdx.x;
    int cnt_in = meta[bh * 2 + 0], NB = meta[bh * 2 + 1];
    int need = NS_ - cnt_in;
    if (t < NB) {
        sc[t] = bscore[(size_t)bh * BANDCAP + t];
        bi[t] = band[(size_t)bh * BANDCAP + t];
    }
    __syncthreads();
    if (t < NB) {
        double mine = sc[t]; int myi = bi[t]; int r = 0;
        for (int j2 = 0; j2 < NB; ++j2)
            r += (sc[j2] > mine) || (sc[j2] == mine && bi[j2] < myi);
        if (r < need) selidx[(size_t)bh * NS_ + cnt_in + r] = myi;
    }
}

// ---------------------------------------------------------------------------
// Kernel 6: partial KV reductions, LDS-staged coalesced. 16 chunks x 256 toks.
// ---------------------------------------------------------------------------
__global__ __launch_bounds__(256) void kv_partial_kernel(
    const float* __restrict__ k32, const ushort* __restrict__ v16,
    float* __restrict__ kvp)
{
    __shared__ float kls[16 * 64];
    __shared__ float vls[16 * 64];
    int ch = blockIdx.x;   // 0..15
    int bh = blockIdx.y;   // 0..63
    int b = bh >> 4, h = bh & 15;
    int t = threadIdx.x;
    int d0 = (t >> 4) * 4, e0 = (t & 15) * 4;
    int lr = t >> 4, lc = (t & 15) * 4;   // staging map: row, col4

    float accC[4][4] = {}, accS[4][4] = {};
    const float* kbase = k32 + (size_t)b * S_ * E_ + h * 64;
    const ushort* vbase = v16 + (size_t)b * S_ * E_ + h * 64;
    int s0 = ch * 256;

    for (int g = 0; g < 16; ++g) {
        int srow = s0 + g * 16 + lr;
        float4 kf = *(const float4*)(kbase + (size_t)srow * E_ + lc);
        ushort4 vu = *(const ushort4*)(vbase + (size_t)srow * E_ + lc);
        __syncthreads();
        *(float4*)&kls[lr * 64 + lc] = kf;
        float4 vf = { bf16_to_f(vu.x), bf16_to_f(vu.y),
                      bf16_to_f(vu.z), bf16_to_f(vu.w) };
        *(float4*)&vls[lr * 64 + lc] = vf;
        __syncthreads();
#pragma unroll 4
        for (int si = 0; si < 16; ++si) {
            int s = s0 + g * 16 + si;
            float th = (float)s * THSTEP;
            float cw = __cosf(th), sw = __sinf(th);
            float4 kf2 = *(const float4*)&kls[si * 64 + d0];
            float4 vf2 = *(const float4*)&vls[si * 64 + e0];
            float kr[4] = { fmaxf(kf2.x, 0.f), fmaxf(kf2.y, 0.f),
                            fmaxf(kf2.z, 0.f), fmaxf(kf2.w, 0.f) };
            float vv[4] = { vf2.x, vf2.y, vf2.z, vf2.w };
            float kc[4], ksn[4];
#pragma unroll
            for (int i = 0; i < 4; i++) { kc[i] = kr[i] * cw; ksn[i] = kr[i] * sw; }
#pragma unroll
            for (int i = 0; i < 4; i++)
#pragma unroll
                for (int jj = 0; jj < 4; jj++) {
                    accC[i][jj] += kc[i] * vv[jj];
                    accS[i][jj] += ksn[i] * vv[jj];
                }
        }
    }
    float* pc = kvp + ((size_t)(bh * 16 + ch) * 2) * 4096;
    float* ps = pc + 4096;
#pragma unroll
    for (int i = 0; i < 4; i++)
#pragma unroll
        for (int jj = 0; jj < 4; jj++) {
            pc[(d0 + i) * 64 + (e0 + jj)] = accC[i][jj];
            ps[(d0 + i) * 64 + (e0 + jj)] = accS[i][jj];
        }
}

// Kernel 7: reduce the 16 partials -> kv[bh][{cos,sin}][64][64]
__global__ __launch_bounds__(256) void kv_reduce_kernel(
    const float* __restrict__ kvp, float* __restrict__ kv)
{
    int i = blockIdx.x * 256 + threadIdx.x;   // 0 .. 64*2*4096-1
    if (i >= 64 * 2 * 4096) return;
    int bh = i >> 13;
    int rem = i & 8191;
    const float* p = kvp + (size_t)bh * 16 * 8192 + rem;
    float a = 0.f;
#pragma unroll
    for (int c = 0; c < 16; c++) a += p[c * 8192];
    kv[i] = a;
}

// ---------------------------------------------------------------------------
// Kernel 8: sampled = qs_cos @ kv_cos + qs_sin @ kv_sin, scattered to out rows
// ---------------------------------------------------------------------------
__global__ __launch_bounds__(256) void sampled_kernel(
    const float* __restrict__ q32, const int* __restrict__ selidx,
    const float* __restrict__ kv, float* __restrict__ out)
{
    __shared__ float kvc[4096];
    __shared__ float kvs[4096];
    int bh = blockIdx.y;
    int b = bh >> 4, h = bh & 15;
    int t = threadIdx.x;
    const float* kvsrc = kv + (size_t)bh * 8192;
    for (int i = t; i < 4096; i += 256) {
        kvc[i] = kvsrc[i];
        kvs[i] = kvsrc[4096 + i];
    }
    __syncthreads();

    int n = blockIdx.x * 256 + t;
    int s = selidx[(size_t)bh * NS_ + n];
    const float* qr = q32 + (size_t)(b * S_ + s) * E_ + h * 64;
    float th = (float)s * THSTEP;
    float cw = __cosf(th), sw = __sinf(th);

    float acc[64];
#pragma unroll
    for (int e = 0; e < 64; e++) acc[e] = 0.f;

    for (int d = 0; d < 64; ++d) {
        float qd = fmaxf(qr[d], 0.f);
        float a = qd * cw, bb = qd * sw;
        const float4* pc4 = (const float4*)&kvc[d * 64];
        const float4* ps4 = (const float4*)&kvs[d * 64];
#pragma unroll
        for (int e4 = 0; e4 < 16; e4++) {
            float4 c4 = pc4[e4], s4 = ps4[e4];
            acc[e4 * 4 + 0] += a * c4.x + bb * s4.x;
            acc[e4 * 4 + 1] += a * c4.y + bb * s4.y;
            acc[e4 * 4 + 2] += a * c4.z + bb * s4.z;
            acc[e4 * 4 + 3] += a * c4.w + bb * s4.w;
        }
    }
    float* orow = out + (size_t)(b * S_ + s) * E_ + h * 64;
#pragma unroll
    for (int e = 0; e < 64; e++) orow[e] = acc[e];
}

__global__ void zero_kernel(uint4* __restrict__ p, int n16)
{
    int stride = gridDim.x * blockDim.x;
    for (int i = blockIdx.x * blockDim.x + threadIdx.x; i < n16; i += stride)
        p[i] = make_uint4(0u, 0u, 0u, 0u);
}

extern "C" void kernel_launch(void* const* d_in, const int* in_sizes, int n_in,
                              void* d_out, int out_size, void* d_ws, size_t ws_size,
                              hipStream_t stream)
{
    const float* x  = (const float*)d_in[0];
    const float* Wq = (const float*)d_in[1];
    const float* bq = (const float*)d_in[2];
    const float* Wk = (const float*)d_in[3];
    const float* bk = (const float*)d_in[4];
    const float* Wv = (const float*)d_in[5];
    const float* bv = (const float*)d_in[6];

    char* ws = (char*)d_ws;
    ushort* xh     = (ushort*)(ws);                   // 33,554,432 B
    float*  kvp    = (float*)(ws);                    // aliases xh (dead after GEMM)
    float*  q32    = (float*)(ws + 33554432);         // 67,108,864 B
    float*  k32    = (float*)(ws + 100663296);        // 67,108,864 B
    ushort* v16    = (ushort*)(ws + 167772160);       // 33,554,432 B
    ushort* Wqh    = (ushort*)(ws + 201326592);       //  2,097,152 B
    ushort* Wql    = (ushort*)(ws + 203423744);
    ushort* Wkh    = (ushort*)(ws + 205520896);
    ushort* Wkl    = (ushort*)(ws + 207618048);
    ushort* Wvh    = (ushort*)(ws + 209715200);
    float*  scores = (float*)(ws + 211812352);        //  1,048,576 B
    int*    selidx = (int*)(ws + 212860928);          //    262,144 B
    int*    band   = (int*)(ws + 213123072);          //     24,576 B
    double* bscore = (double*)(ws + 213147648);       //     49,152 B
    int*    meta   = (int*)(ws + 213196800);          //        512 B
    float*  kv     = (float*)(ws + 213197312);        //  2,097,152 B (end ~205.3 MiB)
    float*  out    = (float*)d_out;

    hipLaunchKernelGGL(zero_kernel, dim3(2048), dim3(256), 0, stream,
                       (uint4*)out, (int)((size_t)M_ * E_ * 4 / 16));
    hipLaunchKernelGGL(split_x_kernel, dim3((M_ * K_) / 1024), dim3(256), 0, stream,
                       x, xh);
    hipLaunchKernelGGL(split_w_kernel, dim3((E_ * E_) / 1024), dim3(256), 0, stream,
                       Wq, Wk, Wv, Wqh, Wql, Wkh, Wkl, Wvh);
    hipLaunchKernelGGL(qkv_gemm, dim3(8, 128, 3), dim3(256), 0, stream,
                       xh, Wqh, Wql, Wkh, Wkl, Wvh, bq, bk, bv, q32, k32, v16);
    hipLaunchKernelGGL(scores_kernel, dim3((B_ * H_ * S_) / 4), dim3(256), 0, stream,
                       q32, k32, scores);
    hipLaunchKernelGGL(band_select_kernel, dim3(B_ * H_), dim3(256), 0, stream,
                       scores, selidx, band, meta);
    hipLaunchKernelGGL(band_exact_kernel, dim3(BANDCAP, B_ * H_), dim3(256), 0, stream,
                       x, Wq, Wk, band, meta, bscore);
    hipLaunchKernelGGL(band_rank_kernel, dim3(B_ * H_), dim3(128), 0, stream,
                       bscore, band, meta, selidx);
    hipLaunchKernelGGL(kv_partial_kernel, dim3(16, 64), dim3(256), 0, stream,
                       k32, v16, kvp);
    hipLaunchKernelGGL(kv_reduce_kernel, dim3(2048), dim3(256), 0, stream,
                       kvp, kv);
    hipLaunchKernelGGL(sampled_kernel, dim3(NS_ / 256, B_ * H_), dim3(256), 0, stream,
                       q32, selidx, kv, out);
}

// Round 7
// 614.234 us; speedup vs baseline: 2.8315x; 1.1380x over previous
//
#include <hip/hip_runtime.h>
#include <hip/hip_bf16.h>

#define B_ 4
#define S_ 4096
#define E_ 1024
#define H_ 16
#define D_ 64
#define NS_ 1024
#define M_ (B_*S_)
#define K_ E_
#define DELTA 0.12f
#define BANDCAP 96

typedef __attribute__((ext_vector_type(8))) short bf16x8;
typedef __attribute__((ext_vector_type(4))) float floatx4;

#define THSTEP 0.00038349519697141023f  /* (pi/2)/4096 */

__device__ inline float bf16_to_f(unsigned short u) {
    return __uint_as_float(((unsigned)u) << 16);
}
__device__ inline unsigned short f_to_bf16(float f) {
    unsigned u = __float_as_uint(f);
    unsigned r = (u + 0x7FFFu + ((u >> 16) & 1u)) >> 16;  // RNE
    return (unsigned short)r;
}

// ---------------------------------------------------------------------------
// Split pass 1: x (fp32) -> xh (bf16 round)
// ---------------------------------------------------------------------------
__global__ __launch_bounds__(256) void split_x_kernel(
    const float* __restrict__ x, ushort* __restrict__ xh)
{
    int i = blockIdx.x * 256 + threadIdx.x;          // over float4s, exact grid
    float4 v = ((const float4*)x)[i];
    ushort4 hh;
    hh.x = f_to_bf16(v.x); hh.y = f_to_bf16(v.y);
    hh.z = f_to_bf16(v.z); hh.w = f_to_bf16(v.w);
    ((ushort4*)xh)[i] = hh;
}

// Split pass 2: Wq,Wk -> hi+lo bf16; Wv -> hi only
__global__ __launch_bounds__(256) void split_w_kernel(
    const float* __restrict__ Wq, const float* __restrict__ Wk,
    const float* __restrict__ Wv,
    ushort* __restrict__ Wqh, ushort* __restrict__ Wql,
    ushort* __restrict__ Wkh, ushort* __restrict__ Wkl,
    ushort* __restrict__ Wvh)
{
    int i = blockIdx.x * 256 + threadIdx.x;          // over float4s, exact grid
    float4 q = ((const float4*)Wq)[i];
    float4 k = ((const float4*)Wk)[i];
    float4 v = ((const float4*)Wv)[i];
    ushort4 h, l;
    h.x=f_to_bf16(q.x); l.x=f_to_bf16(q.x-bf16_to_f(h.x));
    h.y=f_to_bf16(q.y); l.y=f_to_bf16(q.y-bf16_to_f(h.y));
    h.z=f_to_bf16(q.z); l.z=f_to_bf16(q.z-bf16_to_f(h.z));
    h.w=f_to_bf16(q.w); l.w=f_to_bf16(q.w-bf16_to_f(h.w));
    ((ushort4*)Wqh)[i]=h; ((ushort4*)Wql)[i]=l;
    h.x=f_to_bf16(k.x); l.x=f_to_bf16(k.x-bf16_to_f(h.x));
    h.y=f_to_bf16(k.y); l.y=f_to_bf16(k.y-bf16_to_f(h.y));
    h.z=f_to_bf16(k.z); l.z=f_to_bf16(k.z-bf16_to_f(h.z));
    h.w=f_to_bf16(k.w); l.w=f_to_bf16(k.w-bf16_to_f(h.w));
    ((ushort4*)Wkh)[i]=h; ((ushort4*)Wkl)[i]=l;
    h.x=f_to_bf16(v.x); h.y=f_to_bf16(v.y);
    h.z=f_to_bf16(v.z); h.w=f_to_bf16(v.w);
    ((ushort4*)Wvh)[i]=h;
}

// ---------------------------------------------------------------------------
// Kernel 1: QKV GEMM, pure bf16.  SINGLE A-pass: per K-step stage A, Bh, Bl
// and do acc += A*Bh + A*Bl (64 MFMA per barrier-pair vs 32 before; A global
// traffic halved).  Direct load->LDS staging (no cross-barrier register carry
// — R4's carry spilled: WRITE 164MB->2.46GB).
// 128x128 tile, 4 waves, BK=64, XOR-swizzled LDS chunks, ds_read_b128 frags.
// w: 0->q (fp32 out), 1->k (fp32 out), 2->v (bf16 out, hh only)
// ---------------------------------------------------------------------------
__global__ __launch_bounds__(256) void qkv_gemm(
    const ushort* __restrict__ xh,
    const ushort* __restrict__ Wqh, const ushort* __restrict__ Wql,
    const ushort* __restrict__ Wkh, const ushort* __restrict__ Wkl,
    const ushort* __restrict__ Wvh,
    const float* __restrict__ bq, const float* __restrict__ bk,
    const float* __restrict__ bv,
    float* __restrict__ q32, float* __restrict__ k32, ushort* __restrict__ v16)
{
    __shared__ __align__(16) ushort As[128 * 64];
    __shared__ __align__(16) ushort Bsh[128 * 64];
    __shared__ __align__(16) ushort Bsl[128 * 64];

    const int w = blockIdx.z;
    const ushort* Bhp = (w == 0) ? Wqh : (w == 1) ? Wkh : Wvh;
    const ushort* Blp = (w == 0) ? Wql : Wkl;      // unused when w==2
    const float* bias = (w == 0) ? bq : (w == 1) ? bk : bv;
    const bool lo = (w < 2);

    const int m0 = blockIdx.y * 128;
    const int n0 = blockIdx.x * 128;
    const int t = threadIdx.x;
    const int wave = t >> 6, lane = t & 63;
    const int wm = (wave >> 1) * 64, wn = (wave & 1) * 64;
    const int m16 = lane & 15, quad = lane >> 4;

    floatx4 acc[4][4];
#pragma unroll
    for (int i = 0; i < 4; i++)
#pragma unroll
        for (int j = 0; j < 4; j++) acc[i][j] = (floatx4){0.f, 0.f, 0.f, 0.f};

    // per-thread constant staging offsets (32-bit element offsets)
    int aoff[4], boff[4], lofs[4];
#pragma unroll
    for (int i = 0; i < 4; i++) {
        int slot = i * 256 + t;
        int r = slot >> 3, c = slot & 7, g = c ^ (r & 7);
        aoff[i] = (m0 + r) * K_ + g * 8;
        boff[i] = (n0 + r) * K_ + g * 8;
        lofs[i] = slot * 8;
    }

    for (int ks = 0; ks < 16; ++ks) {
        const int kcol = ks * 64;
        // stage: load -> immediately store to LDS (no value lives across a barrier)
#pragma unroll
        for (int i = 0; i < 4; i++) {
            uint4 av = *(const uint4*)(xh + aoff[i] + kcol);
            uint4 bh4 = *(const uint4*)(Bhp + boff[i] + kcol);
            *(uint4*)&As[lofs[i]] = av;
            *(uint4*)&Bsh[lofs[i]] = bh4;
            if (lo) {
                uint4 bl4 = *(const uint4*)(Blp + boff[i] + kcol);
                *(uint4*)&Bsl[lofs[i]] = bl4;
            }
        }
        __syncthreads();

#pragma unroll
        for (int kk = 0; kk < 2; ++kk) {
            bf16x8 af[4], bfr[4];
            const int g = kk * 4 + quad;
#pragma unroll
            for (int mt = 0; mt < 4; ++mt) {
                int r = wm + mt * 16 + m16;
                af[mt] = *(const bf16x8*)&As[(r * 8 + (g ^ (r & 7))) * 8];
            }
#pragma unroll
            for (int nt = 0; nt < 4; ++nt) {
                int r2 = wn + nt * 16 + m16;
                bfr[nt] = *(const bf16x8*)&Bsh[(r2 * 8 + (g ^ (r2 & 7))) * 8];
            }
#pragma unroll
            for (int mt = 0; mt < 4; ++mt)
#pragma unroll
                for (int nt = 0; nt < 4; ++nt)
                    acc[mt][nt] = __builtin_amdgcn_mfma_f32_16x16x32_bf16(
                        af[mt], bfr[nt], acc[mt][nt], 0, 0, 0);
            if (lo) {
#pragma unroll
                for (int nt = 0; nt < 4; ++nt) {
                    int r2 = wn + nt * 16 + m16;
                    bfr[nt] = *(const bf16x8*)&Bsl[(r2 * 8 + (g ^ (r2 & 7))) * 8];
                }
#pragma unroll
                for (int mt = 0; mt < 4; ++mt)
#pragma unroll
                    for (int nt = 0; nt < 4; ++nt)
                        acc[mt][nt] = __builtin_amdgcn_mfma_f32_16x16x32_bf16(
                            af[mt], bfr[nt], acc[mt][nt], 0, 0, 0);
            }
        }
        __syncthreads();
    }

    // epilogue:  C row = quad*4+reg, col = lane&15  [m89/m91 verified layout]
    float biasv[4];
#pragma unroll
    for (int nt = 0; nt < 4; nt++)
        biasv[nt] = bias[n0 + wn + nt * 16 + m16];

    if (w < 2) {
        float* dst = (w == 0) ? q32 : k32;
#pragma unroll
        for (int mt = 0; mt < 4; ++mt)
#pragma unroll
            for (int nt = 0; nt < 4; ++nt) {
                int colg = n0 + wn + nt * 16 + m16;
#pragma unroll
                for (int reg = 0; reg < 4; ++reg) {
                    int rowg = m0 + wm + mt * 16 + quad * 4 + reg;
                    dst[(size_t)rowg * E_ + colg] = acc[mt][nt][reg] + biasv[nt];
                }
            }
    } else {
#pragma unroll
        for (int mt = 0; mt < 4; ++mt)
#pragma unroll
            for (int nt = 0; nt < 4; ++nt) {
                int colg = n0 + wn + nt * 16 + m16;
#pragma unroll
                for (int reg = 0; reg < 4; ++reg) {
                    int rowg = m0 + wm + mt * 16 + quad * 4 + reg;
                    v16[(size_t)rowg * E_ + colg] = f_to_bf16(acc[mt][nt][reg] + biasv[nt]);
                }
            }
    }
}

// ---------------------------------------------------------------------------
// Kernel 2: approx scores[b,h,s] = sum_d q*k (raw q,k fp32). one wave/token
// ---------------------------------------------------------------------------
__global__ __launch_bounds__(256) void scores_kernel(
    const float* __restrict__ q32, const float* __restrict__ k32,
    float* __restrict__ scores)
{
    int wid = blockIdx.x * 4 + (threadIdx.x >> 6);
    int lane = threadIdx.x & 63;
    int s = wid & (S_ - 1);
    int bh = wid >> 12;
    int b = bh >> 4, h = bh & 15;
    size_t addr = (size_t)(b * S_ + s) * E_ + h * 64 + lane;
    float p = q32[addr] * k32[addr];
#pragma unroll
    for (int m = 32; m; m >>= 1) p += __shfl_xor(p, m, 64);
    if (lane == 0) scores[wid] = p;
}

// ---------------------------------------------------------------------------
// Kernel 3: radix-select 1024th approx score T_a; classify into definite-in
// (> T_a+DELTA) and band (|score-T_a| <= DELTA).  Bucket pick via parallel
// suffix-scan (R6 had a serial 256-iter t==0 loop per pass).
// ---------------------------------------------------------------------------
__global__ __launch_bounds__(256) void band_select_kernel(
    const float* __restrict__ scores, int* __restrict__ selidx,
    int* __restrict__ band, int* __restrict__ meta)
{
    __shared__ unsigned keys[4096];
    __shared__ unsigned hist[256];
    __shared__ unsigned suf[256];
    __shared__ unsigned bcast[2];
    __shared__ int cnt_in, cnt_band;

    int bh = blockIdx.x;
    int t = threadIdx.x;
    const float* sc = scores + (size_t)bh * S_;

    for (int i = t; i < 4096; i += 256) {
        unsigned u = __float_as_uint(sc[i]);
        u = (u & 0x80000000u) ? ~u : (u | 0x80000000u);
        keys[i] = u;
    }
    if (t == 0) { cnt_in = 0; cnt_band = 0; }
    __syncthreads();

    unsigned prefix = 0, want = NS_;
    for (int shift = 24; shift >= 0; shift -= 8) {
        hist[t] = 0;
        __syncthreads();
        unsigned pmask = (shift == 24) ? 0u : (0xFFFFFFFFu << (shift + 8));
        for (int i = t; i < 4096; i += 256) {
            unsigned ky = keys[i];
            if ((ky & pmask) == prefix) atomicAdd(&hist[(ky >> shift) & 255u], 1u);
        }
        __syncthreads();
        // suffix sum: suf[t] = sum_{b>=t} hist[b]  (Hillis-Steele, 8 steps)
        suf[t] = hist[t];
        __syncthreads();
        for (int off = 1; off < 256; off <<= 1) {
            unsigned add = (t + off < 256) ? suf[t + off] : 0u;
            __syncthreads();
            suf[t] += add;
            __syncthreads();
        }
        unsigned Sb = suf[t];
        unsigned Snx = (t < 255) ? suf[t + 1] : 0u;
        if (Sb >= want && Snx < want) {          // unique t: S is decreasing
            bcast[0] = (unsigned)t;
            bcast[1] = want - Snx;
        }
        __syncthreads();
        prefix = prefix | (bcast[0] << shift);
        want = bcast[1];
        __syncthreads();
    }
    unsigned fb = (prefix & 0x80000000u) ? (prefix ^ 0x80000000u) : ~prefix;
    float Ta = __uint_as_float(fb);
    float Thi = Ta + DELTA, Tlo = Ta - DELTA;

    int* sel = selidx + (size_t)bh * NS_;
    int* bnd = band + (size_t)bh * BANDCAP;
    for (int i = t; i < 4096; i += 256) {
        float v = sc[i];
        if (v > Thi) {
            int p = atomicAdd(&cnt_in, 1);
            sel[p] = i;
        } else if (v >= Tlo) {
            int p = atomicAdd(&cnt_band, 1);
            if (p < BANDCAP) bnd[p] = i;
        }
    }
    __syncthreads();
    if (t == 0) {
        meta[bh * 2 + 0] = cnt_in;
        meta[bh * 2 + 1] = (cnt_band < BANDCAP) ? cnt_band : BANDCAP;
    }
}

// ---------------------------------------------------------------------------
// Kernel 4: exact fp64 band rescoring — one block per band token, 512 thr
// (8 waves x 16 rows: half the serial row chain of the 256-thr version).
// Coalesced: lane l reads float4 #(l+64p) of the W row.
// ---------------------------------------------------------------------------
__global__ __launch_bounds__(512) void band_exact_kernel(
    const float* __restrict__ x,
    const float* __restrict__ Wq, const float* __restrict__ Wk,
    const int* __restrict__ band, const int* __restrict__ meta,
    double* __restrict__ bscore)
{
    int j = blockIdx.x, bh = blockIdx.y;
    int NB = meta[bh * 2 + 1];
    if (j >= NB) return;
    int b = bh >> 4, h = bh & 15;
    int s = band[(size_t)bh * BANDCAP + j];
    int t = threadIdx.x;
    int wave = t >> 6, lane = t & 63;

    __shared__ float xs[1024];
    __shared__ double qkd[128];     // [0:64)=q dots, [64:128)=k dots

    if (t < 256)
        *(float4*)&xs[t * 4] = *(const float4*)(x + (size_t)(b * S_ + s) * K_ + t * 4);
    __syncthreads();

    // waves 0-3: Wq rows 16*wave.. | waves 4-7: Wk rows 16*(wave-4)..
    const float* Wbase = (wave < 4) ? Wq : Wk;
    int role = wave >> 2;
    int dbase = (wave & 3) * 16;
    const float4* xs4 = (const float4*)xs;

    for (int rr = 0; rr < 16; ++rr) {
        int d = dbase + rr;
        const float4* wrow4 = (const float4*)(Wbase + (size_t)(h * 64 + d) * K_);
        double a = 0.0;
#pragma unroll
        for (int p = 0; p < 4; ++p) {
            float4 wv = wrow4[lane + 64 * p];
            float4 xv = xs4[lane + 64 * p];
            a += (double)xv.x * wv.x + (double)xv.y * wv.y
               + (double)xv.z * wv.z + (double)xv.w * wv.w;
        }
#pragma unroll
        for (int m = 32; m; m >>= 1) a += __shfl_xor(a, m, 64);
        if (lane == 0) qkd[role * 64 + d] = a;
    }
    __syncthreads();

    if (t < 64) {
        double p = qkd[t] * qkd[64 + t];
#pragma unroll
        for (int m = 32; m; m >>= 1) p += __shfl_xor(p, m, 64);
        if (t == 0) bscore[(size_t)bh * BANDCAP + j] = p;
    }
}

// Kernel 5: rank band tokens (ties -> lower index), fill selidx positions.
__global__ __launch_bounds__(128) void band_rank_kernel(
    const double* __restrict__ bscore, const int* __restrict__ band,
    const int* __restrict__ meta, int* __restrict__ selidx)
{
    __shared__ double sc[BANDCAP];
    __shared__ int bi[BANDCAP];
    int bh = blockIdx.x, t = threadIdx.x;
    int cnt_in = meta[bh * 2 + 0], NB = meta[bh * 2 + 1];
    int need = NS_ - cnt_in;
    if (t < NB) {
        sc[t] = bscore[(size_t)bh * BANDCAP + t];
        bi[t] = band[(size_t)bh * BANDCAP + t];
    }
    __syncthreads();
    if (t < NB) {
        double mine = sc[t]; int myi = bi[t]; int r = 0;
        for (int j2 = 0; j2 < NB; ++j2)
            r += (sc[j2] > mine) || (sc[j2] == mine && bi[j2] < myi);
        if (r < need) selidx[(size_t)bh * NS_ + cnt_in + r] = myi;
    }
}

// ---------------------------------------------------------------------------
// Kernel 6: partial KV reductions, LDS-staged coalesced. 16 chunks x 256 toks.
// ---------------------------------------------------------------------------
__global__ __launch_bounds__(256) void kv_partial_kernel(
    const float* __restrict__ k32, const ushort* __restrict__ v16,
    float* __restrict__ kvp)
{
    __shared__ float kls[16 * 64];
    __shared__ float vls[16 * 64];
    int ch = blockIdx.x;   // 0..15
    int bh = blockIdx.y;   // 0..63
    int b = bh >> 4, h = bh & 15;
    int t = threadIdx.x;
    int d0 = (t >> 4) * 4, e0 = (t & 15) * 4;
    int lr = t >> 4, lc = (t & 15) * 4;   // staging map: row, col4

    float accC[4][4] = {}, accS[4][4] = {};
    const float* kbase = k32 + (size_t)b * S_ * E_ + h * 64;
    const ushort* vbase = v16 + (size_t)b * S_ * E_ + h * 64;
    int s0 = ch * 256;

    for (int g = 0; g < 16; ++g) {
        int srow = s0 + g * 16 + lr;
        float4 kf = *(const float4*)(kbase + (size_t)srow * E_ + lc);
        ushort4 vu = *(const ushort4*)(vbase + (size_t)srow * E_ + lc);
        __syncthreads();
        *(float4*)&kls[lr * 64 + lc] = kf;
        float4 vf = { bf16_to_f(vu.x), bf16_to_f(vu.y),
                      bf16_to_f(vu.z), bf16_to_f(vu.w) };
        *(float4*)&vls[lr * 64 + lc] = vf;
        __syncthreads();
#pragma unroll 4
        for (int si = 0; si < 16; ++si) {
            int s = s0 + g * 16 + si;
            float th = (float)s * THSTEP;
            float cw = __cosf(th), sw = __sinf(th);
            float4 kf2 = *(const float4*)&kls[si * 64 + d0];
            float4 vf2 = *(const float4*)&vls[si * 64 + e0];
            float kr[4] = { fmaxf(kf2.x, 0.f), fmaxf(kf2.y, 0.f),
                            fmaxf(kf2.z, 0.f), fmaxf(kf2.w, 0.f) };
            float vv[4] = { vf2.x, vf2.y, vf2.z, vf2.w };
            float kc[4], ksn[4];
#pragma unroll
            for (int i = 0; i < 4; i++) { kc[i] = kr[i] * cw; ksn[i] = kr[i] * sw; }
#pragma unroll
            for (int i = 0; i < 4; i++)
#pragma unroll
                for (int jj = 0; jj < 4; jj++) {
                    accC[i][jj] += kc[i] * vv[jj];
                    accS[i][jj] += ksn[i] * vv[jj];
                }
        }
    }
    float* pc = kvp + ((size_t)(bh * 16 + ch) * 2) * 4096;
    float* ps = pc + 4096;
#pragma unroll
    for (int i = 0; i < 4; i++)
#pragma unroll
        for (int jj = 0; jj < 4; jj++) {
            pc[(d0 + i) * 64 + (e0 + jj)] = accC[i][jj];
            ps[(d0 + i) * 64 + (e0 + jj)] = accS[i][jj];
        }
}

// Kernel 7: reduce the 16 partials -> kv[bh][{cos,sin}][64][64]
__global__ __launch_bounds__(256) void kv_reduce_kernel(
    const float* __restrict__ kvp, float* __restrict__ kv)
{
    int i = blockIdx.x * 256 + threadIdx.x;   // 0 .. 64*2*4096-1
    if (i >= 64 * 2 * 4096) return;
    int bh = i >> 13;
    int rem = i & 8191;
    const float* p = kvp + (size_t)bh * 16 * 8192 + rem;
    float a = 0.f;
#pragma unroll
    for (int c = 0; c < 16; c++) a += p[c * 8192];
    kv[i] = a;
}

// ---------------------------------------------------------------------------
// Kernel 8: sampled = qs_cos @ kv_cos + qs_sin @ kv_sin, scattered to out.
// All gathers/scatters of q rows and out rows go through LDS with coalesced
// per-wave row transfers (R6 version did 64-lanes-64-rows scalar access: 64
// cache lines per instr).  qs padded to stride 65 (kills 64-way bank alias).
// ---------------------------------------------------------------------------
__global__ __launch_bounds__(256) void sampled_kernel(
    const float* __restrict__ q32, const int* __restrict__ selidx,
    const float* __restrict__ kv, float* __restrict__ out)
{
    __shared__ float kvc[4096];
    __shared__ float kvs[4096];
    __shared__ float qs[256 * 65];
    __shared__ int sidx[256];
    int bh = blockIdx.y;
    int b = bh >> 4, h = bh & 15;
    int t = threadIdx.x;
    int wave = t >> 6, lane = t & 63;

    const float* kvsrc = kv + (size_t)bh * 8192;
    for (int i = t; i < 4096; i += 256) {
        kvc[i] = kvsrc[i];
        kvs[i] = kvsrc[4096 + i];
    }
    sidx[t] = selidx[(size_t)bh * NS_ + blockIdx.x * 256 + t];
    __syncthreads();

    // gather q rows, one row per wave-iteration (coalesced 256B loads)
    for (int i = 0; i < 64; ++i) {
        int row = wave * 64 + i;
        int sr = sidx[row];
        qs[row * 65 + lane] = q32[(size_t)(b * S_ + sr) * E_ + h * 64 + lane];
    }
    __syncthreads();

    int s = sidx[t];
    float th = (float)s * THSTEP;
    float cw = __cosf(th), sw = __sinf(th);

    float acc[64];
#pragma unroll
    for (int e = 0; e < 64; e++) acc[e] = 0.f;

    for (int d = 0; d < 64; ++d) {
        float qd = fmaxf(qs[t * 65 + d], 0.f);
        float a = qd * cw, bb = qd * sw;
        const float4* pc4 = (const float4*)&kvc[d * 64];
        const float4* ps4 = (const float4*)&kvs[d * 64];
#pragma unroll
        for (int e4 = 0; e4 < 16; e4++) {
            float4 c4 = pc4[e4], s4 = ps4[e4];
            acc[e4 * 4 + 0] += a * c4.x + bb * s4.x;
            acc[e4 * 4 + 1] += a * c4.y + bb * s4.y;
            acc[e4 * 4 + 2] += a * c4.z + bb * s4.z;
            acc[e4 * 4 + 3] += a * c4.w + bb * s4.w;
        }
    }
    __syncthreads();
#pragma unroll
    for (int e = 0; e < 64; e++) qs[t * 65 + e] = acc[e];
    __syncthreads();

    // scatter result rows, one row per wave-iteration (coalesced 256B stores)
    for (int i = 0; i < 64; ++i) {
        int row = wave * 64 + i;
        int sr = sidx[row];
        out[(size_t)(b * S_ + sr) * E_ + h * 64 + lane] = qs[row * 65 + lane];
    }
}

__global__ void zero_kernel(uint4* __restrict__ p, int n16)
{
    int stride = gridDim.x * blockDim.x;
    for (int i = blockIdx.x * blockDim.x + threadIdx.x; i < n16; i += stride)
        p[i] = make_uint4(0u, 0u, 0u, 0u);
}

extern "C" void kernel_launch(void* const* d_in, const int* in_sizes, int n_in,
                              void* d_out, int out_size, void* d_ws, size_t ws_size,
                              hipStream_t stream)
{
    const float* x  = (const float*)d_in[0];
    const float* Wq = (const float*)d_in[1];
    const float* bq = (const float*)d_in[2];
    const float* Wk = (const float*)d_in[3];
    const float* bk = (const float*)d_in[4];
    const float* Wv = (const float*)d_in[5];
    const float* bv = (const float*)d_in[6];

    char* ws = (char*)d_ws;
    ushort* xh     = (ushort*)(ws);                   // 33,554,432 B
    float*  kvp    = (float*)(ws);                    // aliases xh (dead after GEMM)
    float*  q32    = (float*)(ws + 33554432);         // 67,108,864 B
    float*  k32    = (float*)(ws + 100663296);        // 67,108,864 B
    ushort* v16    = (ushort*)(ws + 167772160);       // 33,554,432 B
    ushort* Wqh    = (ushort*)(ws + 201326592);       //  2,097,152 B
    ushort* Wql    = (ushort*)(ws + 203423744);
    ushort* Wkh    = (ushort*)(ws + 205520896);
    ushort* Wkl    = (ushort*)(ws + 207618048);
    ushort* Wvh    = (ushort*)(ws + 209715200);
    float*  scores = (float*)(ws + 211812352);        //  1,048,576 B
    int*    selidx = (int*)(ws + 212860928);          //    262,144 B
    int*    band   = (int*)(ws + 213123072);          //     24,576 B
    double* bscore = (double*)(ws + 213147648);       //     49,152 B
    int*    meta   = (int*)(ws + 213196800);          //        512 B
    float*  kv     = (float*)(ws + 213197312);        //  2,097,152 B (end ~205.3 MiB)
    float*  out    = (float*)d_out;

    hipLaunchKernelGGL(zero_kernel, dim3(2048), dim3(256), 0, stream,
                       (uint4*)out, (int)((size_t)M_ * E_ * 4 / 16));
    hipLaunchKernelGGL(split_x_kernel, dim3((M_ * K_) / 1024), dim3(256), 0, stream,
                       x, xh);
    hipLaunchKernelGGL(split_w_kernel, dim3((E_ * E_) / 1024), dim3(256), 0, stream,
                       Wq, Wk, Wv, Wqh, Wql, Wkh, Wkl, Wvh);
    hipLaunchKernelGGL(qkv_gemm, dim3(8, 128, 3), dim3(256), 0, stream,
                       xh, Wqh, Wql, Wkh, Wkl, Wvh, bq, bk, bv, q32, k32, v16);
    hipLaunchKernelGGL(scores_kernel, dim3((B_ * H_ * S_) / 4), dim3(256), 0, stream,
                       q32, k32, scores);
    hipLaunchKernelGGL(band_select_kernel, dim3(B_ * H_), dim3(256), 0, stream,
                       scores, selidx, band, meta);
    hipLaunchKernelGGL(band_exact_kernel, dim3(BANDCAP, B_ * H_), dim3(512), 0, stream,
                       x, Wq, Wk, band, meta, bscore);
    hipLaunchKernelGGL(band_rank_kernel, dim3(B_ * H_), dim3(128), 0, stream,
                       bscore, band, meta, selidx);
    hipLaunchKernelGGL(kv_partial_kernel, dim3(16, 64), dim3(256), 0, stream,
                       k32, v16, kvp);
    hipLaunchKernelGGL(kv_reduce_kernel, dim3(2048), dim3(256), 0, stream,
                       kvp, kv);
    hipLaunchKernelGGL(sampled_kernel, dim3(NS_ / 256, B_ * H_), dim3(256), 0, stream,
                       q32, selidx, kv, out);
}